// Round 13
// baseline (248.111 us; speedup 1.0000x reference)
//
#include <hip/hip_runtime.h>
#include <hip/hip_bf16.h>
#include <cstdint>
#include <cstddef>

#define PAD_IDX 200000
#define KN 50
#define MROWS 200001

using frag8 = __attribute__((ext_vector_type(8))) short;
using f32x4 = __attribute__((ext_vector_type(4))) float;
using f32x2 = __attribute__((ext_vector_type(2))) float;

__device__ __forceinline__ short f2bf_rn(float v) {
    __hip_bfloat16 h = __float2bfloat16(v);
    union { __hip_bfloat16 h; short s; } u; u.h = h; return u.s;
}
__device__ __forceinline__ float bf2f(short s) {
    union { uint32_t u; float f; } x; x.u = ((uint32_t)(uint16_t)s) << 16;
    return x.f;
}
__device__ __forceinline__ float sigm(float x) { return 1.f / (1.f + __expf(-x)); }

// native OCP e4m3 converts (gfx950 fp8-conversion-insts)
__device__ __forceinline__ unsigned char f2fp8(float v) {
    int r = __builtin_amdgcn_cvt_pk_fp8_f32(v, v, 0, false);
    return (unsigned char)(r & 0xFF);
}
__device__ __forceinline__ void dec8(uint2 u, float* f) {
    f32x2 v0 = __builtin_amdgcn_cvt_pk_f32_fp8(u.x, false);
    f32x2 v1 = __builtin_amdgcn_cvt_pk_f32_fp8(u.x, true);
    f32x2 v2 = __builtin_amdgcn_cvt_pk_f32_fp8(u.y, false);
    f32x2 v3 = __builtin_amdgcn_cvt_pk_f32_fp8(u.y, true);
    f[0] = v0[0]; f[1] = v0[1]; f[2] = v1[0]; f[3] = v1[1];
    f[4] = v2[0]; f[5] = v2[1]; f[6] = v3[0]; f[7] = v3[1];
}

__device__ __forceinline__ int lstm_perm(int c) {
    int u = c >> 6, g = (c >> 4) & 3, v = c & 15;
    return (g << 9) + (u << 4) + v;
}

// ---------------- fused prep ----------------
__global__ void k_prep(const float* __restrict__ se_W1, const float* __restrict__ se_W2,
                       const float* __restrict__ gcn_W, const float* __restrict__ lin_b,
                       const float* __restrict__ gb,
                       const float* __restrict__ Wih, const float* __restrict__ Whh,
                       short* __restrict__ sw1, short* __restrict__ sw2,
                       short* __restrict__ Bmat, float* __restrict__ bias256,
                       short* __restrict__ Bih, short* __restrict__ Bhh) {
    int b = blockIdx.x, t = threadIdx.x;
    if (b < 512) {
        int i = b * 256 + t;
        sw1[i] = f2bf_rn(se_W1[i]);
    } else if (b < 1024) {
        int i = (b - 512) * 256 + t;
        sw2[i] = f2bf_rn(se_W2[i]);
    } else if (b < 1152) {
        int i = (b - 1024) * 256 + t;
        int n = i >> 7, k = i & 127;
        float v = (n < 128) ? gcn_W[n * 256 + k] : gcn_W[(n - 128) * 256 + 128 + k];
        Bmat[i] = f2bf_rn(v);
        if (k == 0) bias256[n] = (n < 128) ? 0.f : (lin_b[n - 128] + gb[n - 128]);
    } else {
        int i = (b - 1152) * 256 + t;   // 0 .. 2048*512
        int c = i >> 9, k = i & 511;
        int n = lstm_perm(c);
        if (k < 256) Bih[c * 256 + k] = f2bf_rn(Wih[n * 256 + k]);
        else         Bhh[c * 256 + (k - 256)] = f2bf_rn(Whh[(size_t)n * 512 + (k - 256)]);
    }
}

// ---------------- streaming table kernel v5: FP8 (e4m3, x16 scale) output ----------------

#define NT_TAB 3126   // ceil(200001/64)

#define TAB_ISSUE(PV, m0i) {                                                   \
    int row_ = (m0i) + rbase + l15;                                            \
    const float* p_ = emb + (size_t)row_ * 128 + (lk << 3);                    \
    if (row_ < MROWS) {                                                        \
        PV[0] = *reinterpret_cast<const float4*>(p_);                          \
        PV[1] = *reinterpret_cast<const float4*>(p_ + 4);                      \
        PV[2] = *reinterpret_cast<const float4*>(p_ + 32);                     \
        PV[3] = *reinterpret_cast<const float4*>(p_ + 36);                     \
        PV[4] = *reinterpret_cast<const float4*>(p_ + 64);                     \
        PV[5] = *reinterpret_cast<const float4*>(p_ + 68);                     \
        PV[6] = *reinterpret_cast<const float4*>(p_ + 96);                     \
        PV[7] = *reinterpret_cast<const float4*>(p_ + 100);                    \
    } else {                                                                   \
        PV[0] = z4; PV[1] = z4; PV[2] = z4; PV[3] = z4;                        \
        PV[4] = z4; PV[5] = z4; PV[6] = z4; PV[7] = z4;                        \
    } }

#define TAB_COMPUTE(PV, m0i) {                                                 \
    f32x4 acc[8] = {};                                                         \
    _Pragma("unroll")                                                          \
    for (int kf = 0; kf < 4; ++kf) {                                           \
        float4 vlo = PV[kf * 2], vhi = PV[kf * 2 + 1];                         \
        frag8 av;                                                              \
        av[0] = f2bf_rn(vlo.x); av[1] = f2bf_rn(vlo.y);                        \
        av[2] = f2bf_rn(vlo.z); av[3] = f2bf_rn(vlo.w);                        \
        av[4] = f2bf_rn(vhi.x); av[5] = f2bf_rn(vhi.y);                        \
        av[6] = f2bf_rn(vhi.z); av[7] = f2bf_rn(vhi.w);                        \
        _Pragma("unroll")                                                      \
        for (int fn = 0; fn < 8; ++fn) {                                       \
            frag8 bf = *reinterpret_cast<const frag8*>(                        \
                &Bs2[((fn * 4 + kf) * 64 + lane) * 8]);                        \
            acc[fn] = __builtin_amdgcn_mfma_f32_16x16x32_bf16(av, bf, acc[fn], 0, 0, 0); \
        }                                                                      \
    }                                                                          \
    _Pragma("unroll")                                                          \
    for (int fn = 0; fn < 8; ++fn)                                             \
        _Pragma("unroll")                                                      \
        for (int j = 0; j < 4; ++j)                                            \
            bounce8[(rbase + (lk << 2) + j) * 272 + fn * 16 + l15] =           \
                f2fp8((acc[fn][j] + bc[fn]) * 16.f);                           \
    _Pragma("unroll")                                                          \
    for (int p = 0; p < 2; ++p) {                                              \
        int idx = p * 64 + lane;                                               \
        int rl = idx >> 3, ch = idx & 7;                                       \
        int grow = (m0i) + rbase + rl;                                         \
        if (grow < MROWS) {                                                    \
            int4 v = *reinterpret_cast<const int4*>(&bounce8[(rbase + rl) * 272 + ch * 16]); \
            *reinterpret_cast<int4*>(T + (size_t)grow * 256 + n0 + ch * 16) = v; \
        }                                                                      \
    } }

__global__ __launch_bounds__(256, 3) void k_table(
    const float* __restrict__ emb, const short* __restrict__ Bmat,
    const float* __restrict__ bias256, unsigned char* __restrict__ T)
{
    __shared__ short Bs2[32 * 64 * 8];                        // 32 KB frag-linear B
    __shared__ __align__(16) unsigned char bounce8[64 * 272]; // 17 KB fp8 bounce
    const int t = threadIdx.x, lane = t & 63, w = t >> 6;
    const int n0 = blockIdx.x * 128;
    const int l15 = lane & 15, lk = lane >> 4;
    const int rbase = w * 16;
    const float4 z4 = {0.f, 0.f, 0.f, 0.f};

#pragma unroll
    for (int i = 0; i < 8; ++i) {
        int slot = i * 256 + t;          // 0..2047
        int fk = slot >> 6, ln = slot & 63;
        int fn = fk >> 2, kf = fk & 3;
        frag8 bv = *reinterpret_cast<const frag8*>(
            Bmat + (n0 + fn * 16 + (ln & 15)) * 128 + kf * 32 + ((ln >> 4) << 3));
        *reinterpret_cast<frag8*>(&Bs2[slot * 8]) = bv;
    }
    float bc[8];
#pragma unroll
    for (int fn = 0; fn < 8; ++fn) bc[fn] = bias256[n0 + fn * 16 + l15];
    __syncthreads();

    float4 pvA[8], pvB[8];
    int tile = blockIdx.y;
    const int stride = gridDim.y;
    if (tile < NT_TAB) TAB_ISSUE(pvA, tile * 64);
    for (; tile < NT_TAB; tile += 2 * stride) {
        int t1 = tile + stride;
        if (t1 < NT_TAB) TAB_ISSUE(pvB, t1 * 64);
        TAB_COMPUTE(pvA, tile * 64);
        int t2 = tile + 2 * stride;
        if (t2 < NT_TAB) TAB_ISSUE(pvA, t2 * 64);
        if (t1 < NT_TAB) TAB_COMPUTE(pvB, t1 * 64);
    }
}

// ---------------- generic MFMA GEMM: C = A@B^T (+bias) ----------------

constexpr int SA = 40;
constexpr int CS = 132;

template<bool RELU, bool OUTBF>
__global__ __launch_bounds__(256) void gemm_bt(
    const short* __restrict__ A, int lda, const short* __restrict__ B, int ldb,
    float* __restrict__ C, short* __restrict__ Cbf, int ldc,
    const float* __restrict__ bias, int M, int N, int K)
{
    __shared__ short sh[2 * 128 * SA];
    short* As = sh;
    short* Bs = sh + 128 * SA;
    const int t = threadIdx.x;
    const int m0 = blockIdx.y * 128, n0 = blockIdx.x * 128;
    const int wave = t >> 6, lane = t & 63;
    const int wr = wave >> 1, wc = wave & 1;
    f32x4 acc[4][4] = {};
    for (int k0 = 0; k0 < K; k0 += 32) {
#pragma unroll
        for (int i = 0; i < 2; ++i) {
            int idx = t + i * 256;
            int r = idx >> 2, c8 = (idx & 3) << 3;
            frag8 av = {0, 0, 0, 0, 0, 0, 0, 0};
            int arow = m0 + r;
            if (arow < M)
                av = *reinterpret_cast<const frag8*>(A + (size_t)arow * lda + k0 + c8);
            *reinterpret_cast<frag8*>(&As[r * SA + c8]) = av;
            frag8 bv = *reinterpret_cast<const frag8*>(B + (size_t)(n0 + r) * ldb + k0 + c8);
            *reinterpret_cast<frag8*>(&Bs[r * SA + c8]) = bv;
        }
        __syncthreads();
        frag8 af[4], bfv[4];
#pragma unroll
        for (int f = 0; f < 4; ++f) {
            af[f]  = *reinterpret_cast<const frag8*>(&As[(wr * 64 + f * 16 + (lane & 15)) * SA + ((lane >> 4) << 3)]);
            bfv[f] = *reinterpret_cast<const frag8*>(&Bs[(wc * 64 + f * 16 + (lane & 15)) * SA + ((lane >> 4) << 3)]);
        }
#pragma unroll
        for (int fm = 0; fm < 4; ++fm)
#pragma unroll
            for (int fn = 0; fn < 4; ++fn)
                acc[fm][fn] = __builtin_amdgcn_mfma_f32_16x16x32_bf16(af[fm], bfv[fn], acc[fm][fn], 0, 0, 0);
        __syncthreads();
    }

    if constexpr (OUTBF) {
#pragma unroll
        for (int half = 0; half < 2; ++half) {
            if (wr == half) {
#pragma unroll
                for (int fm = 0; fm < 4; ++fm) {
                    int rl = fm * 16 + ((lane >> 4) << 2);
#pragma unroll
                    for (int fn = 0; fn < 4; ++fn) {
                        int col = wc * 64 + fn * 16 + (lane & 15);
                        float bcv = bias[n0 + col];
#pragma unroll
                        for (int j = 0; j < 4; ++j) {
                            float v = acc[fm][fn][j] + bcv;
                            if (RELU) v = fmaxf(v, 0.f);
                            sh[(rl + j) * CS + col] = f2bf_rn(v);
                        }
                    }
                }
            }
            __syncthreads();
#pragma unroll
            for (int p = 0; p < 4; ++p) {
                int off16 = p * 256 + t;
                int rl = off16 >> 4, ch = off16 & 15;
                int rr = m0 + half * 64 + rl;
                if (rr < M) {
                    frag8 val = *reinterpret_cast<const frag8*>(&sh[rl * CS + ch * 8]);
                    *reinterpret_cast<frag8*>(&Cbf[(size_t)rr * ldc + n0 + ch * 8]) = val;
                }
            }
            __syncthreads();
        }
    } else {
#pragma unroll
        for (int fm = 0; fm < 4; ++fm) {
            int rowb = m0 + wr * 64 + fm * 16 + ((lane >> 4) << 2);
#pragma unroll
            for (int fn = 0; fn < 4; ++fn) {
                int col = n0 + wc * 64 + fn * 16 + (lane & 15);
                float bcv = bias[col];
#pragma unroll
                for (int j = 0; j < 4; ++j) {
                    int rr = rowb + j;
                    if (rr < M) {
                        float v = acc[fm][fn][j] + bcv;
                        if (RELU) v = fmaxf(v, 0.f);
                        C[(size_t)rr * ldc + col] = v;
                    }
                }
            }
        }
    }
}

// ---------------- G0 GEMM + fused LSTM step 0 ----------------

__global__ __launch_bounds__(256) void gemm_g0(
    const short* __restrict__ A, const short* __restrict__ Bih,
    const float* __restrict__ bias_a, float* __restrict__ cbuf,
    const float* __restrict__ enc, short* __restrict__ AHnext,
    short* __restrict__ G0b)
{
    __shared__ short sh[2 * 128 * SA];
    short* As = sh;
    short* Bs = sh + 128 * SA;
    const int t = threadIdx.x;
    const int m0 = blockIdx.y * 128, n0 = blockIdx.x * 128;
    const int wave = t >> 6, lane = t & 63;
    const int wr = wave >> 1, wc = wave & 1;
    f32x4 acc[4][4] = {};
    for (int k0 = 0; k0 < 256; k0 += 32) {
#pragma unroll
        for (int i = 0; i < 2; ++i) {
            int idx = t + i * 256;
            int r = idx >> 2, c8 = (idx & 3) << 3;
            frag8 av = *reinterpret_cast<const frag8*>(A + (size_t)(m0 + r) * 512 + k0 + c8);
            *reinterpret_cast<frag8*>(&As[r * SA + c8]) = av;
            frag8 bv = *reinterpret_cast<const frag8*>(Bih + (size_t)(n0 + r) * 256 + k0 + c8);
            *reinterpret_cast<frag8*>(&Bs[r * SA + c8]) = bv;
        }
        __syncthreads();
        frag8 af[4], bfv[4];
#pragma unroll
        for (int f = 0; f < 4; ++f) {
            af[f]  = *reinterpret_cast<const frag8*>(&As[(wr * 64 + f * 16 + (lane & 15)) * SA + ((lane >> 4) << 3)]);
            bfv[f] = *reinterpret_cast<const frag8*>(&Bs[(wc * 64 + f * 16 + (lane & 15)) * SA + ((lane >> 4) << 3)]);
        }
#pragma unroll
        for (int fm = 0; fm < 4; ++fm)
#pragma unroll
            for (int fn = 0; fn < 4; ++fn)
                acc[fm][fn] = __builtin_amdgcn_mfma_f32_16x16x32_bf16(af[fm], bfv[fn], acc[fm][fn], 0, 0, 0);
        __syncthreads();
    }

    const int v = lane & 15;
    const int colbase = n0 + wc * 64;
    const int j = ((blockIdx.x * 2 + wc) << 4) + v;   // unit 0..511
    float bv0 = bias_a[colbase + v];
    float bv1 = bias_a[colbase + 16 + v];
    float bv2 = bias_a[colbase + 32 + v];
    float bv3 = bias_a[colbase + 48 + v];
#pragma unroll
    for (int fm = 0; fm < 4; ++fm) {
        int rowb = m0 + wr * 64 + fm * 16 + ((lane >> 4) << 2);
#pragma unroll
        for (int jr = 0; jr < 4; ++jr) {
            int row = rowb + jr;
            float gi = acc[fm][0][jr] + bv0;
            float gf = acc[fm][1][jr] + bv1;
            float gg = acc[fm][2][jr] + bv2;
            float go = acc[fm][3][jr] + bv3;
            short4 g4;
            g4.x = f2bf_rn(gi); g4.y = f2bf_rn(gf);
            g4.z = f2bf_rn(gg); g4.w = f2bf_rn(go);
            *reinterpret_cast<short4*>(G0b + ((size_t)row * 512 + j) * 4) = g4;
            float cn = sigm(gi) * tanhf(gg);          // c_prev = 0
            cbuf[(size_t)row * 512 + j] = cn;
            float hc = sigm(go) * tanhf(cn);
            if (j < 256) {
                float hv = enc[(size_t)row * 256 + j] + hc;
                AHnext[(size_t)row * 512 + 256 + j] = f2bf_rn(hv);
            }
        }
    }
}

// ---------------- LSTM steps 1-3 ----------------

__global__ __launch_bounds__(256) void gemm_lstm2(
    const short* __restrict__ A, const short* __restrict__ Bp,
    const short* __restrict__ G0b, const float* __restrict__ whh_r,
    float* __restrict__ cbuf, const float* __restrict__ enc,
    float* __restrict__ hbuf, short* __restrict__ AHnext, int last)
{
    __shared__ short sh[2 * 128 * SA];
    short* As = sh;
    short* Bs = sh + 128 * SA;
    const int t = threadIdx.x;
    const int m0 = blockIdx.y * 128, n0 = blockIdx.x * 128;
    const int wave = t >> 6, lane = t & 63;
    const int wr = wave >> 1, wc = wave & 1;
    f32x4 acc[4][4] = {};
    for (int k0 = 0; k0 < 256; k0 += 32) {
#pragma unroll
        for (int i = 0; i < 2; ++i) {
            int idx = t + i * 256;
            int r = idx >> 2, c8 = (idx & 3) << 3;
            frag8 av = *reinterpret_cast<const frag8*>(A + (size_t)(m0 + r) * 512 + k0 + c8);
            *reinterpret_cast<frag8*>(&As[r * SA + c8]) = av;
            frag8 bv = *reinterpret_cast<const frag8*>(Bp + (size_t)(n0 + r) * 256 + k0 + c8);
            *reinterpret_cast<frag8*>(&Bs[r * SA + c8]) = bv;
        }
        __syncthreads();
        frag8 af[4], bfv[4];
#pragma unroll
        for (int f = 0; f < 4; ++f) {
            af[f]  = *reinterpret_cast<const frag8*>(&As[(wr * 64 + f * 16 + (lane & 15)) * SA + ((lane >> 4) << 3)]);
            bfv[f] = *reinterpret_cast<const frag8*>(&Bs[(wc * 64 + f * 16 + (lane & 15)) * SA + ((lane >> 4) << 3)]);
        }
#pragma unroll
        for (int fm = 0; fm < 4; ++fm)
#pragma unroll
            for (int fn = 0; fn < 4; ++fn)
                acc[fm][fn] = __builtin_amdgcn_mfma_f32_16x16x32_bf16(af[fm], bfv[fn], acc[fm][fn], 0, 0, 0);
        __syncthreads();
    }

    const int v = lane & 15;
    const int colbase = n0 + wc * 64;
    const int j = ((blockIdx.x * 2 + wc) << 4) + v;
    float wr0 = whh_r[colbase + v];
    float wr1 = whh_r[colbase + 16 + v];
    float wr2 = whh_r[colbase + 32 + v];
    float wr3 = whh_r[colbase + 48 + v];
#pragma unroll
    for (int fm = 0; fm < 4; ++fm) {
        int rowb = m0 + wr * 64 + fm * 16 + ((lane >> 4) << 2);
#pragma unroll
        for (int jr = 0; jr < 4; ++jr) {
            int row = rowb + jr;
            short4 g4 = *reinterpret_cast<const short4*>(G0b + ((size_t)row * 512 + j) * 4);
            float gi = acc[fm][0][jr] + bf2f(g4.x) + wr0;
            float gf = acc[fm][1][jr] + bf2f(g4.y) + wr1;
            float gg = acc[fm][2][jr] + bf2f(g4.z) + wr2;
            float go = acc[fm][3][jr] + bf2f(g4.w) + wr3;
            size_t cidx = (size_t)row * 512 + j;
            float cn = sigm(gf) * cbuf[cidx] + sigm(gi) * tanhf(gg);
            cbuf[cidx] = cn;
            float hc = sigm(go) * tanhf(cn);
            if (j < 256) {
                float hv = enc[(size_t)row * 256 + j] + hc;
                AHnext[(size_t)row * 512 + 256 + j] = f2bf_rn(hv);
                if (last) hbuf[(size_t)row * 256 + j] = hv;
            }
        }
    }
}

// ---------------- fused neigh v8: 4 independent waves/block (1 row each), no barriers ----------------

__global__ __launch_bounds__(256) void k_neigh(
    const int* __restrict__ q_l1, const int* __restrict__ q_deg_l,
    const int* __restrict__ q_r1, const int* __restrict__ q_deg_r,
    const int* __restrict__ s_l1, const int* __restrict__ s_deg_l,
    const int* __restrict__ s_r1, const int* __restrict__ s_deg_r,
    const int* __restrict__ query, const int* __restrict__ support,
    const float* __restrict__ emb, const unsigned char* __restrict__ T,
    const float* __restrict__ cg_W1, const float* __restrict__ cg_b1,
    const float* __restrict__ cg_ln_g, const float* __restrict__ cg_ln_b,
    const float* __restrict__ cg_W2, const float* __restrict__ cg_b2,
    const float* __restrict__ temp_p,
    float* __restrict__ outv, short* __restrict__ outbf)
{
    const int wv = threadIdx.x >> 6;        // wave 0..3 = row within block
    const int lane = threadIdx.x & 63;
    int b = blockIdx.x * 4 + wv;
    const bool active = b < 8202;
    if (!active) b = 0;

    const int* conns; const int* deg; const int* ids2; int side, n, orow;
    if (b < 4096)      { conns = q_l1; deg = q_deg_l; ids2 = query;   side = 0; n = b;        orow = n; }
    else if (b < 8192) { conns = q_r1; deg = q_deg_r; ids2 = query;   side = 1; n = b - 4096; orow = n; }
    else if (b < 8197) { conns = s_l1; deg = s_deg_l; ids2 = support; side = 0; n = b - 8192; orow = 4096 + n; }
    else               { conns = s_r1; deg = s_deg_r; ids2 = support; side = 1; n = b - 8197; orow = 4096 + n; }

    // per-wave LDS slices (no cross-wave sharing -> no __syncthreads needed)
    __shared__ __align__(16) float se[4][128];
    __shared__ int rels[4][64], ents[4][64];
    __shared__ __align__(16) float aggs[4][128];

    int self_id = ids2[n * 2 + side];
    se[wv][lane]      = emb[(size_t)self_id * 128 + lane];
    se[wv][lane + 64] = emb[(size_t)self_id * 128 + 64 + lane];
    if (lane < KN) {
        rels[wv][lane] = conns[((size_t)n * KN + lane) * 2];
        ents[wv][lane] = conns[((size_t)n * KN + lane) * 2 + 1];
    }

    const int dg = lane & 15, kq = lane >> 4;
    const int d0 = dg << 3;
    float se0[8];
    *reinterpret_cast<float4*>(&se0[0]) = *reinterpret_cast<const float4*>(&se[wv][d0]);
    *reinterpret_cast<float4*>(&se0[4]) = *reinterpret_cast<const float4*>(&se[wv][d0 + 4]);

    // thread's k set: k = 4*it + kq, it in [0,13); invalid/PAD masked via pmask
    uint2 ra0, ra1, ra2, ra3, ra4, ra5, ra6, ra7, ra8, ra9, ra10, ra11, ra12;
    uint2 rb0, rb1, rb2, rb3, rb4, rb5, rb6, rb7, rb8, rb9, rb10, rb11, rb12;
    int pmask = 0;

#define NB_LOAD(IT, RA, RB) {                                                  \
        int k_ = IT * 4 + kq;                                                  \
        int kc = k_ < KN ? k_ : KN - 1;                                        \
        int rv = rels[wv][kc], ev = ents[wv][kc];                              \
        if (k_ >= KN || rv == PAD_IDX) pmask |= (1 << IT);                     \
        RA = *reinterpret_cast<const uint2*>(T + (size_t)rv * 256 + d0);       \
        RB = *reinterpret_cast<const uint2*>(T + (size_t)ev * 256 + 128 + d0); }
    NB_LOAD(0, ra0, rb0)   NB_LOAD(1, ra1, rb1)   NB_LOAD(2, ra2, rb2)
    NB_LOAD(3, ra3, rb3)   NB_LOAD(4, ra4, rb4)   NB_LOAD(5, ra5, rb5)
    NB_LOAD(6, ra6, rb6)   NB_LOAD(7, ra7, rb7)   NB_LOAD(8, ra8, rb8)
    NB_LOAD(9, ra9, rb9)   NB_LOAD(10, ra10, rb10) NB_LOAD(11, ra11, rb11)
    NB_LOAD(12, ra12, rb12)
#undef NB_LOAD

    // scores: decode + leaky + pack bf16 (kept for agg) + partial dot + 16-lane reduce
    frag8 pk0, pk1, pk2, pk3, pk4, pk5, pk6, pk7, pk8, pk9, pk10, pk11, pk12;
    float sc0, sc1, sc2, sc3, sc4, sc5, sc6, sc7, sc8, sc9, sc10, sc11, sc12;
#define NB_SCORE(IT, RA, RB, PK, SC) {                                         \
        float fa[8], fb[8]; dec8(RA, fa); dec8(RB, fb);                        \
        float prt = 0.f; frag8 pv;                                             \
        _Pragma("unroll")                                                      \
        for (int q = 0; q < 8; ++q) {                                          \
            float raw = (fa[q] + fb[q]) * 0.0625f;                             \
            float pl = raw > 0.f ? raw : 0.01f * raw;                          \
            pv[q] = f2bf_rn(pl);                                               \
            prt += pl * se0[q];                                                \
        }                                                                      \
        prt += __shfl_xor(prt, 1); prt += __shfl_xor(prt, 2);                  \
        prt += __shfl_xor(prt, 4); prt += __shfl_xor(prt, 8);                  \
        PK = pv;                                                               \
        SC = (pmask >> IT) & 1 ? -1e9f : prt; }
    NB_SCORE(0, ra0, rb0, pk0, sc0)     NB_SCORE(1, ra1, rb1, pk1, sc1)
    NB_SCORE(2, ra2, rb2, pk2, sc2)     NB_SCORE(3, ra3, rb3, pk3, sc3)
    NB_SCORE(4, ra4, rb4, pk4, sc4)     NB_SCORE(5, ra5, rb5, pk5, sc5)
    NB_SCORE(6, ra6, rb6, pk6, sc6)     NB_SCORE(7, ra7, rb7, pk7, sc7)
    NB_SCORE(8, ra8, rb8, pk8, sc8)     NB_SCORE(9, ra9, rb9, pk9, sc9)
    NB_SCORE(10, ra10, rb10, pk10, sc10) NB_SCORE(11, ra11, rb11, pk11, sc11)
    NB_SCORE(12, ra12, rb12, pk12, sc12)
#undef NB_SCORE

    // softmax over all 50 k's, fully in-register
    float lm = sc0;
    lm = fmaxf(lm, sc1);  lm = fmaxf(lm, sc2);  lm = fmaxf(lm, sc3);
    lm = fmaxf(lm, sc4);  lm = fmaxf(lm, sc5);  lm = fmaxf(lm, sc6);
    lm = fmaxf(lm, sc7);  lm = fmaxf(lm, sc8);  lm = fmaxf(lm, sc9);
    lm = fmaxf(lm, sc10); lm = fmaxf(lm, sc11); lm = fmaxf(lm, sc12);
    lm = fmaxf(lm, __shfl_xor(lm, 16));
    lm = fmaxf(lm, __shfl_xor(lm, 32));
    float w0 = __expf(sc0 - lm),  w1 = __expf(sc1 - lm),  w2 = __expf(sc2 - lm);
    float w3 = __expf(sc3 - lm),  w4 = __expf(sc4 - lm),  w5 = __expf(sc5 - lm);
    float w6 = __expf(sc6 - lm),  w7 = __expf(sc7 - lm),  w8 = __expf(sc8 - lm);
    float w9 = __expf(sc9 - lm),  w10 = __expf(sc10 - lm), w11 = __expf(sc11 - lm);
    float w12 = __expf(sc12 - lm);
    float ls = w0 + w1 + w2 + w3 + w4 + w5 + w6 + w7 + w8 + w9 + w10 + w11 + w12;
    ls += __shfl_xor(ls, 16);
    ls += __shfl_xor(ls, 32);
    float winv = 1.f / ls;

    // agg: unpack bf16 (cheap), weighted accumulate, reduce across kq
    float agg8[8] = {};
#define NB_AGG(PK, W) {                                                        \
        _Pragma("unroll")                                                      \
        for (int q = 0; q < 8; ++q) agg8[q] += W * bf2f(PK[q]); }
    NB_AGG(pk0, w0)   NB_AGG(pk1, w1)   NB_AGG(pk2, w2)
    NB_AGG(pk3, w3)   NB_AGG(pk4, w4)   NB_AGG(pk5, w5)
    NB_AGG(pk6, w6)   NB_AGG(pk7, w7)   NB_AGG(pk8, w8)
    NB_AGG(pk9, w9)   NB_AGG(pk10, w10) NB_AGG(pk11, w11)
    NB_AGG(pk12, w12)
#undef NB_AGG
#pragma unroll
    for (int q = 0; q < 8; ++q) {
        float a = agg8[q] * winv;
        a += __shfl_xor(a, 16);
        a += __shfl_xor(a, 32);
        agg8[q] = a;
    }
    if (kq == 0) {
#pragma unroll
        for (int q = 0; q < 8; ++q) aggs[wv][d0 + q] = agg8[q];
    }

    // gate: all 64 lanes of this wave, one cg_W1 row each
    const float4* w1p = reinterpret_cast<const float4*>(cg_W1 + lane * 128);
    const float4* a4 = reinterpret_cast<const float4*>(&aggs[wv][0]);
    float acc = cg_b1[lane];
#pragma unroll 8
    for (int d = 0; d < 32; ++d) {
        float4 a = a4[d], ww = w1p[d];
        acc += a.x * ww.x + a.y * ww.y + a.z * ww.z + a.w * ww.w;
    }
    float s = acc;
    for (int o = 32; o; o >>= 1) s += __shfl_xor(s, o);
    float mean = s * (1.f / 64.f);
    float dv = acc - mean;
    float vs = dv * dv;
    for (int o = 32; o; o >>= 1) vs += __shfl_xor(vs, o);
    float var = vs * (1.f / 64.f);
    float hv = dv * rsqrtf(var + 1e-5f) * cg_ln_g[lane] + cg_ln_b[lane];
    hv = fmaxf(hv, 0.f);
    float lg = hv * cg_W2[lane];
    for (int o = 32; o; o >>= 1) lg += __shfl_xor(lg, o);
    lg += cg_b2[0];
    float temp = fminf(fmaxf(temp_p[0], 0.1f), 5.0f);
    float gate = sigm(lg / temp);
    float gate_s = (deg[n] > 0) ? gate : 0.f;

    if (active) {
#pragma unroll
        for (int h = 0; h < 2; ++h) {
            int d = lane + h * 64;
            float o = tanhf(se[wv][d] + gate_s * aggs[wv][d]);
            size_t off = (size_t)orow * 256 + (size_t)side * 128 + d;
            outv[off] = o;
            outbf[off] = f2bf_rn(o);
        }
    }
}

// ---------------- LN (+residual) ----------------

__global__ void k_ln(const float* __restrict__ se2out, const float* __restrict__ x,
                     const float* __restrict__ g, const float* __restrict__ b,
                     float* __restrict__ enc, short* __restrict__ AHa, int M) {
    int wave = threadIdx.x >> 6, lane = threadIdx.x & 63;
    int row = blockIdx.x * 4 + wave;
    if (row >= M) return;
    const float* pr = se2out + (size_t)row * 256;
    const float* px = x + (size_t)row * 256;
    float v[4];
    float s = 0.f;
#pragma unroll
    for (int i = 0; i < 4; ++i) { v[i] = pr[lane + 64 * i] + px[lane + 64 * i]; s += v[i]; }
    for (int o = 32; o; o >>= 1) s += __shfl_xor(s, o);
    float mean = s * (1.f / 256.f);
    float vs = 0.f;
#pragma unroll
    for (int i = 0; i < 4; ++i) { float d = v[i] - mean; vs += d * d; }
    for (int o = 32; o; o >>= 1) vs += __shfl_xor(vs, o);
    float inv = rsqrtf(vs * (1.f / 256.f) + 1e-5f);
#pragma unroll
    for (int i = 0; i < 4; ++i) {
        int col = lane + 64 * i;
        float ov = (v[i] - mean) * inv * g[col] + b[col];
        enc[(size_t)row * 256 + col] = ov;
        if (row < 4096) AHa[(size_t)row * 512 + col] = f2bf_rn(ov);
    }
}

// ---------------- support mean + permuted LSTM biases ----------------

__global__ void k_whhbias(const float* __restrict__ enc, const float* __restrict__ Whh,
                          const float* __restrict__ bih, const float* __restrict__ bhh,
                          float* __restrict__ sg, float* __restrict__ bias_a,
                          float* __restrict__ whh_r) {
    __shared__ __align__(16) float sgs[256];
    int t = threadIdx.x;
    float s0 = 0.f;
#pragma unroll
    for (int i = 0; i < 5; ++i) s0 += enc[(size_t)(4096 + i) * 256 + t];
    s0 *= 0.2f;
    sgs[t] = s0;
    if (blockIdx.x == 0) sg[t] = s0;
    __syncthreads();

    int c = blockIdx.x * 256 + t;
    int nn = lstm_perm(c);
    const float4* wr = reinterpret_cast<const float4*>(Whh + (size_t)nn * 512 + 256);
    const float4* g4 = reinterpret_cast<const float4*>(sgs);
    float s = 0.f;
#pragma unroll 8
    for (int q = 0; q < 64; ++q) {
        float4 a = g4[q], ww = wr[q];
        s += a.x * ww.x + a.y * ww.y + a.z * ww.z + a.w * ww.w;
    }
    bias_a[c] = bih[nn] + bhh[nn];
    whh_r[c] = s;
}

__global__ void k_dot(const float* __restrict__ h, const float* __restrict__ gvec,
                      float* __restrict__ out) {
    int wave = threadIdx.x >> 6, lane = threadIdx.x & 63;
    int n = blockIdx.x * 4 + wave;
    if (n >= 4096) return;
    const float* p = h + (size_t)n * 256;
    float s = 0.f;
#pragma unroll
    for (int i = 0; i < 4; ++i) s += p[lane + 64 * i] * gvec[lane + 64 * i];
    for (int o = 32; o; o >>= 1) s += __shfl_xor(s, o);
    if (!lane) out[n] = s;
}

// ---------------- launch ----------------

extern "C" void kernel_launch(void* const* d_in, const int* in_sizes, int n_in,
                              void* d_out, int out_size, void* d_ws, size_t ws_size,
                              hipStream_t stream) {
    const int* query     = (const int*)d_in[0];
    const int* support   = (const int*)d_in[1];
    const int* q_l1      = (const int*)d_in[2];
    const int* q_deg_l   = (const int*)d_in[3];
    const int* q_r1      = (const int*)d_in[4];
    const int* q_deg_r   = (const int*)d_in[5];
    const int* s_l1      = (const int*)d_in[6];
    const int* s_deg_l   = (const int*)d_in[7];
    const int* s_r1      = (const int*)d_in[8];
    const int* s_deg_r   = (const int*)d_in[9];
    const float* emb     = (const float*)d_in[10];
    const float* gcn_W   = (const float*)d_in[11];
    const float* gcn_lin_b = (const float*)d_in[12];
    const float* gcn_b   = (const float*)d_in[13];
    const float* gate_temp = (const float*)d_in[14];
    const float* cg_W1   = (const float*)d_in[15];
    const float* cg_b1   = (const float*)d_in[16];
    const float* cg_ln_g = (const float*)d_in[17];
    const float* cg_ln_b = (const float*)d_in[18];
    const float* cg_W2   = (const float*)d_in[19];
    const float* cg_b2   = (const float*)d_in[20];
    const float* se_W1   = (const float*)d_in[21];
    const float* se_b1   = (const float*)d_in[22];
    const float* se_W2   = (const float*)d_in[23];
    const float* se_b2   = (const float*)d_in[24];
    const float* se_ln_g = (const float*)d_in[25];
    const float* se_ln_b = (const float*)d_in[26];
    const float* lstm_Wih = (const float*)d_in[27];
    const float* lstm_Whh = (const float*)d_in[28];
    const float* lstm_bih = (const float*)d_in[29];
    const float* lstm_bhh = (const float*)d_in[30];

    char* ws = (char*)d_ws;
    unsigned char* T = (unsigned char*)(ws + 0);    // 200001*256 fp8 = 51,200,256 (dead after neigh)
    short* h1bf    = (short*)(ws + 0);              // overlay
    float* se2out  = (float*)(ws + 4199424);
    float* enc     = (float*)(ws + 8398848);
    float* cbuf    = (float*)(ws + 12598272);       // 4096*512*4
    float* hbuf    = (float*)(ws + 20986880);       // 4096*256*4
    short* AHa     = (short*)(ws + 25181184);       // 4096*512*2
    short* AHb     = (short*)(ws + 29375488);       // 4096*512*2
    short* G0b     = (short*)(ws + 33569792);       // 16,777,216
    float* qsvec   = (float*)(ws + 102400512);
    short* qsbf    = (short*)(ws + 106599936);
    short* Bmat    = (short*)(ws + 108699648);
    float* bias256 = (float*)(ws + 108765184);
    short* sw1     = (short*)(ws + 108766208);
    short* sw2     = (short*)(ws + 109028352);
    short* Bih     = (short*)(ws + 109290496);
    short* Bhh     = (short*)(ws + 110339072);
    float* sg      = (float*)(ws + 111387648);
    float* bias_a  = (float*)(ws + 111388672);
    float* whh_r   = (float*)(ws + 111396864);
    float* outp    = (float*)d_out;

    k_prep<<<5248, 256, 0, stream>>>(se_W1, se_W2, gcn_W, gcn_lin_b, gcn_b,
                                     lstm_Wih, lstm_Whh, sw1, sw2, Bmat, bias256, Bih, Bhh);

    k_table<<<dim3(2, 384), 256, 0, stream>>>(emb, Bmat, bias256, T);

    k_neigh<<<2051, 256, 0, stream>>>(q_l1, q_deg_l, q_r1, q_deg_r,
        s_l1, s_deg_l, s_r1, s_deg_r, query, support, emb, T,
        cg_W1, cg_b1, cg_ln_g, cg_ln_b, cg_W2, cg_b2, gate_temp, qsvec, qsbf);

    gemm_bt<true, true><<<dim3(4, 33), 256, 0, stream>>>(
        qsbf, 256, sw1, 256, nullptr, h1bf, 512, se_b1, 4101, 512, 256);
    gemm_bt<false, false><<<dim3(2, 33), 256, 0, stream>>>(
        h1bf, 512, sw2, 512, se2out, nullptr, 256, se_b2, 4101, 256, 512);
    k_ln<<<1026, 256, 0, stream>>>(se2out, qsvec, se_ln_g, se_ln_b, enc, AHa, 4101);

    k_whhbias<<<8, 256, 0, stream>>>(enc, lstm_Whh, lstm_bih, lstm_bhh, sg, bias_a, whh_r);

    gemm_g0<<<dim3(16, 32), 256, 0, stream>>>(AHa, Bih, bias_a, cbuf, enc, AHb, G0b);

    gemm_lstm2<<<dim3(16, 32), 256, 0, stream>>>(
        AHb + 256, Bhh, G0b, whh_r, cbuf, enc, hbuf, AHa, 0);
    gemm_lstm2<<<dim3(16, 32), 256, 0, stream>>>(
        AHa + 256, Bhh, G0b, whh_r, cbuf, enc, hbuf, AHb, 0);
    gemm_lstm2<<<dim3(16, 32), 256, 0, stream>>>(
        AHb + 256, Bhh, G0b, whh_r, cbuf, enc, hbuf, AHa, 1);

    k_dot<<<1024, 256, 0, stream>>>(hbuf, sg, outp);
}

// Round 14
// 236.494 us; speedup vs baseline: 1.0491x; 1.0491x over previous
//
#include <hip/hip_runtime.h>
#include <hip/hip_bf16.h>
#include <cstdint>
#include <cstddef>

#define PAD_IDX 200000
#define KN 50
#define MROWS 200001

using frag8 = __attribute__((ext_vector_type(8))) short;
using f32x4 = __attribute__((ext_vector_type(4))) float;
using f32x2 = __attribute__((ext_vector_type(2))) float;

__device__ __forceinline__ short f2bf_rn(float v) {
    __hip_bfloat16 h = __float2bfloat16(v);
    union { __hip_bfloat16 h; short s; } u; u.h = h; return u.s;
}
__device__ __forceinline__ float bf2f(short s) {
    union { uint32_t u; float f; } x; x.u = ((uint32_t)(uint16_t)s) << 16;
    return x.f;
}
__device__ __forceinline__ float sigm(float x) { return 1.f / (1.f + __expf(-x)); }

// native OCP e4m3 converts (gfx950 fp8-conversion-insts)
__device__ __forceinline__ unsigned char f2fp8(float v) {
    int r = __builtin_amdgcn_cvt_pk_fp8_f32(v, v, 0, false);
    return (unsigned char)(r & 0xFF);
}
__device__ __forceinline__ void dec8(uint2 u, float* f) {
    f32x2 v0 = __builtin_amdgcn_cvt_pk_f32_fp8(u.x, false);
    f32x2 v1 = __builtin_amdgcn_cvt_pk_f32_fp8(u.x, true);
    f32x2 v2 = __builtin_amdgcn_cvt_pk_f32_fp8(u.y, false);
    f32x2 v3 = __builtin_amdgcn_cvt_pk_f32_fp8(u.y, true);
    f[0] = v0[0]; f[1] = v0[1]; f[2] = v1[0]; f[3] = v1[1];
    f[4] = v2[0]; f[5] = v2[1]; f[6] = v3[0]; f[7] = v3[1];
}

__device__ __forceinline__ int lstm_perm(int c) {
    int u = c >> 6, g = (c >> 4) & 3, v = c & 15;
    return (g << 9) + (u << 4) + v;
}

// ---------------- fused prep ----------------
__global__ void k_prep(const float* __restrict__ se_W1, const float* __restrict__ se_W2,
                       const float* __restrict__ gcn_W, const float* __restrict__ lin_b,
                       const float* __restrict__ gb,
                       const float* __restrict__ Wih, const float* __restrict__ Whh,
                       short* __restrict__ sw1, short* __restrict__ sw2,
                       short* __restrict__ Bmat, float* __restrict__ bias256,
                       short* __restrict__ Bih, short* __restrict__ Bhh) {
    int b = blockIdx.x, t = threadIdx.x;
    if (b < 512) {
        int i = b * 256 + t;
        sw1[i] = f2bf_rn(se_W1[i]);
    } else if (b < 1024) {
        int i = (b - 512) * 256 + t;
        sw2[i] = f2bf_rn(se_W2[i]);
    } else if (b < 1152) {
        int i = (b - 1024) * 256 + t;
        int n = i >> 7, k = i & 127;
        float v = (n < 128) ? gcn_W[n * 256 + k] : gcn_W[(n - 128) * 256 + 128 + k];
        Bmat[i] = f2bf_rn(v);
        if (k == 0) bias256[n] = (n < 128) ? 0.f : (lin_b[n - 128] + gb[n - 128]);
    } else {
        int i = (b - 1152) * 256 + t;   // 0 .. 2048*512
        int c = i >> 9, k = i & 511;
        int n = lstm_perm(c);
        if (k < 256) Bih[c * 256 + k] = f2bf_rn(Wih[n * 256 + k]);
        else         Bhh[c * 256 + (k - 256)] = f2bf_rn(Whh[(size_t)n * 512 + (k - 256)]);
    }
}

// ---------------- streaming table kernel v5: FP8 (e4m3, x16 scale) output ----------------

#define NT_TAB 3126   // ceil(200001/64)

#define TAB_ISSUE(PV, m0i) {                                                   \
    int row_ = (m0i) + rbase + l15;                                            \
    const float* p_ = emb + (size_t)row_ * 128 + (lk << 3);                    \
    if (row_ < MROWS) {                                                        \
        PV[0] = *reinterpret_cast<const float4*>(p_);                          \
        PV[1] = *reinterpret_cast<const float4*>(p_ + 4);                      \
        PV[2] = *reinterpret_cast<const float4*>(p_ + 32);                     \
        PV[3] = *reinterpret_cast<const float4*>(p_ + 36);                     \
        PV[4] = *reinterpret_cast<const float4*>(p_ + 64);                     \
        PV[5] = *reinterpret_cast<const float4*>(p_ + 68);                     \
        PV[6] = *reinterpret_cast<const float4*>(p_ + 96);                     \
        PV[7] = *reinterpret_cast<const float4*>(p_ + 100);                    \
    } else {                                                                   \
        PV[0] = z4; PV[1] = z4; PV[2] = z4; PV[3] = z4;                        \
        PV[4] = z4; PV[5] = z4; PV[6] = z4; PV[7] = z4;                        \
    } }

#define TAB_COMPUTE(PV, m0i) {                                                 \
    f32x4 acc[8] = {};                                                         \
    _Pragma("unroll")                                                          \
    for (int kf = 0; kf < 4; ++kf) {                                           \
        float4 vlo = PV[kf * 2], vhi = PV[kf * 2 + 1];                         \
        frag8 av;                                                              \
        av[0] = f2bf_rn(vlo.x); av[1] = f2bf_rn(vlo.y);                        \
        av[2] = f2bf_rn(vlo.z); av[3] = f2bf_rn(vlo.w);                        \
        av[4] = f2bf_rn(vhi.x); av[5] = f2bf_rn(vhi.y);                        \
        av[6] = f2bf_rn(vhi.z); av[7] = f2bf_rn(vhi.w);                        \
        _Pragma("unroll")                                                      \
        for (int fn = 0; fn < 8; ++fn) {                                       \
            frag8 bf = *reinterpret_cast<const frag8*>(                        \
                &Bs2[((fn * 4 + kf) * 64 + lane) * 8]);                        \
            acc[fn] = __builtin_amdgcn_mfma_f32_16x16x32_bf16(av, bf, acc[fn], 0, 0, 0); \
        }                                                                      \
    }                                                                          \
    _Pragma("unroll")                                                          \
    for (int fn = 0; fn < 8; ++fn)                                             \
        _Pragma("unroll")                                                      \
        for (int j = 0; j < 4; ++j)                                            \
            bounce8[(rbase + (lk << 2) + j) * 272 + fn * 16 + l15] =           \
                f2fp8((acc[fn][j] + bc[fn]) * 16.f);                           \
    _Pragma("unroll")                                                          \
    for (int p = 0; p < 2; ++p) {                                              \
        int idx = p * 64 + lane;                                               \
        int rl = idx >> 3, ch = idx & 7;                                       \
        int grow = (m0i) + rbase + rl;                                         \
        if (grow < MROWS) {                                                    \
            int4 v = *reinterpret_cast<const int4*>(&bounce8[(rbase + rl) * 272 + ch * 16]); \
            *reinterpret_cast<int4*>(T + (size_t)grow * 256 + n0 + ch * 16) = v; \
        }                                                                      \
    } }

__global__ __launch_bounds__(256, 3) void k_table(
    const float* __restrict__ emb, const short* __restrict__ Bmat,
    const float* __restrict__ bias256, unsigned char* __restrict__ T)
{
    __shared__ short Bs2[32 * 64 * 8];                        // 32 KB frag-linear B
    __shared__ __align__(16) unsigned char bounce8[64 * 272]; // 17 KB fp8 bounce
    const int t = threadIdx.x, lane = t & 63, w = t >> 6;
    const int n0 = blockIdx.x * 128;
    const int l15 = lane & 15, lk = lane >> 4;
    const int rbase = w * 16;
    const float4 z4 = {0.f, 0.f, 0.f, 0.f};

#pragma unroll
    for (int i = 0; i < 8; ++i) {
        int slot = i * 256 + t;          // 0..2047
        int fk = slot >> 6, ln = slot & 63;
        int fn = fk >> 2, kf = fk & 3;
        frag8 bv = *reinterpret_cast<const frag8*>(
            Bmat + (n0 + fn * 16 + (ln & 15)) * 128 + kf * 32 + ((ln >> 4) << 3));
        *reinterpret_cast<frag8*>(&Bs2[slot * 8]) = bv;
    }
    float bc[8];
#pragma unroll
    for (int fn = 0; fn < 8; ++fn) bc[fn] = bias256[n0 + fn * 16 + l15];
    __syncthreads();

    float4 pvA[8], pvB[8];
    int tile = blockIdx.y;
    const int stride = gridDim.y;
    if (tile < NT_TAB) TAB_ISSUE(pvA, tile * 64);
    for (; tile < NT_TAB; tile += 2 * stride) {
        int t1 = tile + stride;
        if (t1 < NT_TAB) TAB_ISSUE(pvB, t1 * 64);
        TAB_COMPUTE(pvA, tile * 64);
        int t2 = tile + 2 * stride;
        if (t2 < NT_TAB) TAB_ISSUE(pvA, t2 * 64);
        if (t1 < NT_TAB) TAB_COMPUTE(pvB, t1 * 64);
    }
}

// ---------------- generic MFMA GEMM: C = A@B^T (+bias) ----------------

constexpr int SA = 40;
constexpr int CS = 132;

template<bool RELU, bool OUTBF>
__global__ __launch_bounds__(256) void gemm_bt(
    const short* __restrict__ A, int lda, const short* __restrict__ B, int ldb,
    float* __restrict__ C, short* __restrict__ Cbf, int ldc,
    const float* __restrict__ bias, int M, int N, int K)
{
    __shared__ short sh[2 * 128 * SA];
    short* As = sh;
    short* Bs = sh + 128 * SA;
    const int t = threadIdx.x;
    const int m0 = blockIdx.y * 128, n0 = blockIdx.x * 128;
    const int wave = t >> 6, lane = t & 63;
    const int wr = wave >> 1, wc = wave & 1;
    f32x4 acc[4][4] = {};
    for (int k0 = 0; k0 < K; k0 += 32) {
#pragma unroll
        for (int i = 0; i < 2; ++i) {
            int idx = t + i * 256;
            int r = idx >> 2, c8 = (idx & 3) << 3;
            frag8 av = {0, 0, 0, 0, 0, 0, 0, 0};
            int arow = m0 + r;
            if (arow < M)
                av = *reinterpret_cast<const frag8*>(A + (size_t)arow * lda + k0 + c8);
            *reinterpret_cast<frag8*>(&As[r * SA + c8]) = av;
            frag8 bv = *reinterpret_cast<const frag8*>(B + (size_t)(n0 + r) * ldb + k0 + c8);
            *reinterpret_cast<frag8*>(&Bs[r * SA + c8]) = bv;
        }
        __syncthreads();
        frag8 af[4], bfv[4];
#pragma unroll
        for (int f = 0; f < 4; ++f) {
            af[f]  = *reinterpret_cast<const frag8*>(&As[(wr * 64 + f * 16 + (lane & 15)) * SA + ((lane >> 4) << 3)]);
            bfv[f] = *reinterpret_cast<const frag8*>(&Bs[(wc * 64 + f * 16 + (lane & 15)) * SA + ((lane >> 4) << 3)]);
        }
#pragma unroll
        for (int fm = 0; fm < 4; ++fm)
#pragma unroll
            for (int fn = 0; fn < 4; ++fn)
                acc[fm][fn] = __builtin_amdgcn_mfma_f32_16x16x32_bf16(af[fm], bfv[fn], acc[fm][fn], 0, 0, 0);
        __syncthreads();
    }

    if constexpr (OUTBF) {
#pragma unroll
        for (int half = 0; half < 2; ++half) {
            if (wr == half) {
#pragma unroll
                for (int fm = 0; fm < 4; ++fm) {
                    int rl = fm * 16 + ((lane >> 4) << 2);
#pragma unroll
                    for (int fn = 0; fn < 4; ++fn) {
                        int col = wc * 64 + fn * 16 + (lane & 15);
                        float bcv = bias[n0 + col];
#pragma unroll
                        for (int j = 0; j < 4; ++j) {
                            float v = acc[fm][fn][j] + bcv;
                            if (RELU) v = fmaxf(v, 0.f);
                            sh[(rl + j) * CS + col] = f2bf_rn(v);
                        }
                    }
                }
            }
            __syncthreads();
#pragma unroll
            for (int p = 0; p < 4; ++p) {
                int off16 = p * 256 + t;
                int rl = off16 >> 4, ch = off16 & 15;
                int rr = m0 + half * 64 + rl;
                if (rr < M) {
                    frag8 val = *reinterpret_cast<const frag8*>(&sh[rl * CS + ch * 8]);
                    *reinterpret_cast<frag8*>(&Cbf[(size_t)rr * ldc + n0 + ch * 8]) = val;
                }
            }
            __syncthreads();
        }
    } else {
#pragma unroll
        for (int fm = 0; fm < 4; ++fm) {
            int rowb = m0 + wr * 64 + fm * 16 + ((lane >> 4) << 2);
#pragma unroll
            for (int fn = 0; fn < 4; ++fn) {
                int col = n0 + wc * 64 + fn * 16 + (lane & 15);
                float bcv = bias[col];
#pragma unroll
                for (int j = 0; j < 4; ++j) {
                    int rr = rowb + j;
                    if (rr < M) {
                        float v = acc[fm][fn][j] + bcv;
                        if (RELU) v = fmaxf(v, 0.f);
                        C[(size_t)rr * ldc + col] = v;
                    }
                }
            }
        }
    }
}

// ---------------- G0 GEMM + fused LSTM step 0 (G0 stored fp8 e4m3, x8 scale) ----------------

__global__ __launch_bounds__(256) void gemm_g0(
    const short* __restrict__ A, const short* __restrict__ Bih,
    const float* __restrict__ bias_a, float* __restrict__ cbuf,
    const float* __restrict__ enc, short* __restrict__ AHnext,
    unsigned char* __restrict__ G0f)
{
    __shared__ short sh[2 * 128 * SA];
    short* As = sh;
    short* Bs = sh + 128 * SA;
    const int t = threadIdx.x;
    const int m0 = blockIdx.y * 128, n0 = blockIdx.x * 128;
    const int wave = t >> 6, lane = t & 63;
    const int wr = wave >> 1, wc = wave & 1;
    f32x4 acc[4][4] = {};
    for (int k0 = 0; k0 < 256; k0 += 32) {
#pragma unroll
        for (int i = 0; i < 2; ++i) {
            int idx = t + i * 256;
            int r = idx >> 2, c8 = (idx & 3) << 3;
            frag8 av = *reinterpret_cast<const frag8*>(A + (size_t)(m0 + r) * 512 + k0 + c8);
            *reinterpret_cast<frag8*>(&As[r * SA + c8]) = av;
            frag8 bv = *reinterpret_cast<const frag8*>(Bih + (size_t)(n0 + r) * 256 + k0 + c8);
            *reinterpret_cast<frag8*>(&Bs[r * SA + c8]) = bv;
        }
        __syncthreads();
        frag8 af[4], bfv[4];
#pragma unroll
        for (int f = 0; f < 4; ++f) {
            af[f]  = *reinterpret_cast<const frag8*>(&As[(wr * 64 + f * 16 + (lane & 15)) * SA + ((lane >> 4) << 3)]);
            bfv[f] = *reinterpret_cast<const frag8*>(&Bs[(wc * 64 + f * 16 + (lane & 15)) * SA + ((lane >> 4) << 3)]);
        }
#pragma unroll
        for (int fm = 0; fm < 4; ++fm)
#pragma unroll
            for (int fn = 0; fn < 4; ++fn)
                acc[fm][fn] = __builtin_amdgcn_mfma_f32_16x16x32_bf16(af[fm], bfv[fn], acc[fm][fn], 0, 0, 0);
        __syncthreads();
    }

    const int v = lane & 15;
    const int colbase = n0 + wc * 64;
    const int j = ((blockIdx.x * 2 + wc) << 4) + v;   // unit 0..511
    float bv0 = bias_a[colbase + v];
    float bv1 = bias_a[colbase + 16 + v];
    float bv2 = bias_a[colbase + 32 + v];
    float bv3 = bias_a[colbase + 48 + v];
#pragma unroll
    for (int fm = 0; fm < 4; ++fm) {
        int rowb = m0 + wr * 64 + fm * 16 + ((lane >> 4) << 2);
#pragma unroll
        for (int jr = 0; jr < 4; ++jr) {
            int row = rowb + jr;
            float gi = acc[fm][0][jr] + bv0;
            float gf = acc[fm][1][jr] + bv1;
            float gg = acc[fm][2][jr] + bv2;
            float go = acc[fm][3][jr] + bv3;
            int r8 = __builtin_amdgcn_cvt_pk_fp8_f32(gi * 8.f, gf * 8.f, 0, false);
            r8 = __builtin_amdgcn_cvt_pk_fp8_f32(gg * 8.f, go * 8.f, r8, true);
            *reinterpret_cast<unsigned int*>(G0f + ((size_t)row * 512 + j) * 4) = (unsigned int)r8;
            float cn = sigm(gi) * tanhf(gg);          // c_prev = 0
            cbuf[(size_t)row * 512 + j] = cn;
            float hc = sigm(go) * tanhf(cn);
            if (j < 256) {
                float hv = enc[(size_t)row * 256 + j] + hc;
                AHnext[(size_t)row * 512 + 256 + j] = f2bf_rn(hv);
            }
        }
    }
}

// ---------------- LSTM steps 1-3 ----------------

__global__ __launch_bounds__(256) void gemm_lstm2(
    const short* __restrict__ A, const short* __restrict__ Bp,
    const unsigned char* __restrict__ G0f, const float* __restrict__ whh_r,
    float* __restrict__ cbuf, const float* __restrict__ enc,
    float* __restrict__ hbuf, short* __restrict__ AHnext, int last)
{
    __shared__ short sh[2 * 128 * SA];
    short* As = sh;
    short* Bs = sh + 128 * SA;
    const int t = threadIdx.x;
    const int m0 = blockIdx.y * 128, n0 = blockIdx.x * 128;
    const int wave = t >> 6, lane = t & 63;
    const int wr = wave >> 1, wc = wave & 1;
    f32x4 acc[4][4] = {};
    for (int k0 = 0; k0 < 256; k0 += 32) {
#pragma unroll
        for (int i = 0; i < 2; ++i) {
            int idx = t + i * 256;
            int r = idx >> 2, c8 = (idx & 3) << 3;
            frag8 av = *reinterpret_cast<const frag8*>(A + (size_t)(m0 + r) * 512 + k0 + c8);
            *reinterpret_cast<frag8*>(&As[r * SA + c8]) = av;
            frag8 bv = *reinterpret_cast<const frag8*>(Bp + (size_t)(n0 + r) * 256 + k0 + c8);
            *reinterpret_cast<frag8*>(&Bs[r * SA + c8]) = bv;
        }
        __syncthreads();
        frag8 af[4], bfv[4];
#pragma unroll
        for (int f = 0; f < 4; ++f) {
            af[f]  = *reinterpret_cast<const frag8*>(&As[(wr * 64 + f * 16 + (lane & 15)) * SA + ((lane >> 4) << 3)]);
            bfv[f] = *reinterpret_cast<const frag8*>(&Bs[(wc * 64 + f * 16 + (lane & 15)) * SA + ((lane >> 4) << 3)]);
        }
#pragma unroll
        for (int fm = 0; fm < 4; ++fm)
#pragma unroll
            for (int fn = 0; fn < 4; ++fn)
                acc[fm][fn] = __builtin_amdgcn_mfma_f32_16x16x32_bf16(af[fm], bfv[fn], acc[fm][fn], 0, 0, 0);
        __syncthreads();
    }

    const int v = lane & 15;
    const int colbase = n0 + wc * 64;
    const int j = ((blockIdx.x * 2 + wc) << 4) + v;
    float wr0 = whh_r[colbase + v];
    float wr1 = whh_r[colbase + 16 + v];
    float wr2 = whh_r[colbase + 32 + v];
    float wr3 = whh_r[colbase + 48 + v];
#pragma unroll
    for (int fm = 0; fm < 4; ++fm) {
        int rowb = m0 + wr * 64 + fm * 16 + ((lane >> 4) << 2);
#pragma unroll
        for (int jr = 0; jr < 4; ++jr) {
            int row = rowb + jr;
            unsigned int u = *reinterpret_cast<const unsigned int*>(G0f + ((size_t)row * 512 + j) * 4);
            f32x2 g01 = __builtin_amdgcn_cvt_pk_f32_fp8(u, false);
            f32x2 g23 = __builtin_amdgcn_cvt_pk_f32_fp8(u, true);
            float gi = acc[fm][0][jr] + g01[0] * 0.125f + wr0;
            float gf = acc[fm][1][jr] + g01[1] * 0.125f + wr1;
            float gg = acc[fm][2][jr] + g23[0] * 0.125f + wr2;
            float go = acc[fm][3][jr] + g23[1] * 0.125f + wr3;
            size_t cidx = (size_t)row * 512 + j;
            float cn = sigm(gf) * cbuf[cidx] + sigm(gi) * tanhf(gg);
            cbuf[cidx] = cn;
            float hc = sigm(go) * tanhf(cn);
            if (j < 256) {
                float hv = enc[(size_t)row * 256 + j] + hc;
                AHnext[(size_t)row * 512 + 256 + j] = f2bf_rn(hv);
                if (last) hbuf[(size_t)row * 256 + j] = hv;
            }
        }
    }
}

// ---------------- fused neigh v9: round-11 v6 shape + branch-free clamped loads ----------------

constexpr int PS2 = 136;

__global__ __launch_bounds__(128) void k_neigh(
    const int* __restrict__ q_l1, const int* __restrict__ q_deg_l,
    const int* __restrict__ q_r1, const int* __restrict__ q_deg_r,
    const int* __restrict__ s_l1, const int* __restrict__ s_deg_l,
    const int* __restrict__ s_r1, const int* __restrict__ s_deg_r,
    const int* __restrict__ query, const int* __restrict__ support,
    const float* __restrict__ emb, const unsigned char* __restrict__ T,
    const float* __restrict__ cg_W1, const float* __restrict__ cg_b1,
    const float* __restrict__ cg_ln_g, const float* __restrict__ cg_ln_b,
    const float* __restrict__ cg_W2, const float* __restrict__ cg_b2,
    const float* __restrict__ temp_p,
    float* __restrict__ outv, short* __restrict__ outbf)
{
    int b = blockIdx.x;
    const int* conns; const int* deg; const int* ids2; int side, n, orow;
    if (b < 4096)      { conns = q_l1; deg = q_deg_l; ids2 = query;   side = 0; n = b;        orow = n; }
    else if (b < 8192) { conns = q_r1; deg = q_deg_r; ids2 = query;   side = 1; n = b - 4096; orow = n; }
    else if (b < 8197) { conns = s_l1; deg = s_deg_l; ids2 = support; side = 0; n = b - 8192; orow = 4096 + n; }
    else               { conns = s_r1; deg = s_deg_r; ids2 = support; side = 1; n = b - 8197; orow = 4096 + n; }

    int t = threadIdx.x;  // 128
    __shared__ __align__(16) short projb[KN * PS2];
    __shared__ __align__(16) float se[128];
    __shared__ int rels[KN], ents[KN];
    __shared__ float wts[KN];
    __shared__ float scs[KN];
    __shared__ __align__(16) float aggs[128];
    __shared__ float gate_s;

    int self_id = ids2[n * 2 + side];
    float self_e = emb[(size_t)self_id * 128 + t];
    se[t] = self_e;
    if (t < KN) {
        rels[t] = conns[((size_t)n * KN + t) * 2];
        ents[t] = conns[((size_t)n * KN + t) * 2 + 1];
    }
    __syncthreads();

    // gather + score: k = it*8 + (t>>4), d0 = (t&15)*8.
    // Loads are branch-free (clamped index, PAD/invalid masked via pmask) so the
    // compiler can batch all 14 into flight; only the LDS store is guarded.
    {
        const int kq = t >> 4;
        const int d0 = (t & 15) << 3;
        uint2 ra0, ra1, ra2, ra3, ra4, ra5, ra6;
        uint2 rb0, rb1, rb2, rb3, rb4, rb5, rb6;
        int pmask = 0;

#define NB_LOAD(IT, RA, RB) {                                                  \
        int k_ = IT * 8 + kq;                                                  \
        int kc = k_ < KN ? k_ : KN - 1;                                        \
        int rv = rels[kc], ev = ents[kc];                                      \
        if (k_ >= KN || rv == PAD_IDX) pmask |= (1 << IT);                     \
        RA = *reinterpret_cast<const uint2*>(T + (size_t)rv * 256 + d0);       \
        RB = *reinterpret_cast<const uint2*>(T + (size_t)ev * 256 + 128 + d0); }
        NB_LOAD(0, ra0, rb0)
        NB_LOAD(1, ra1, rb1)
        NB_LOAD(2, ra2, rb2)
        NB_LOAD(3, ra3, rb3)
        NB_LOAD(4, ra4, rb4)
        NB_LOAD(5, ra5, rb5)
        NB_LOAD(6, ra6, rb6)
#undef NB_LOAD

        float se0[8];
        *reinterpret_cast<float4*>(&se0[0]) = *reinterpret_cast<const float4*>(&se[d0]);
        *reinterpret_cast<float4*>(&se0[4]) = *reinterpret_cast<const float4*>(&se[d0 + 4]);

#define NB_PROC(IT, RA, RB) {                                                  \
        int k_ = IT * 8 + kq;                                                  \
        float fa[8], fb[8]; dec8(RA, fa); dec8(RB, fb);                        \
        frag8 pv; float prt = 0.f;                                             \
        _Pragma("unroll")                                                      \
        for (int q = 0; q < 8; ++q) {                                          \
            float raw = (fa[q] + fb[q]) * 0.0625f;                             \
            float pl = raw > 0.f ? raw : 0.01f * raw;                          \
            pv[q] = f2bf_rn(pl);                                               \
            prt += pl * se0[q];                                                \
        }                                                                      \
        prt += __shfl_xor(prt, 1); prt += __shfl_xor(prt, 2);                  \
        prt += __shfl_xor(prt, 4); prt += __shfl_xor(prt, 8);                  \
        if (k_ < KN) {                                                         \
            *reinterpret_cast<frag8*>(&projb[k_ * PS2 + d0]) = pv;             \
            if ((t & 15) == 0)                                                 \
                scs[k_] = ((pmask >> IT) & 1) ? -1e9f : prt;                   \
        } }
        NB_PROC(0, ra0, rb0)
        NB_PROC(1, ra1, rb1)
        NB_PROC(2, ra2, rb2)
        NB_PROC(3, ra3, rb3)
        NB_PROC(4, ra4, rb4)
        NB_PROC(5, ra5, rb5)
        NB_PROC(6, ra6, rb6)
#undef NB_PROC
    }
    __syncthreads();

    if (t < 64) {
        float sc = (t < KN) ? scs[t] : -1e9f;
        float m = sc;
        for (int o = 32; o; o >>= 1) m = fmaxf(m, __shfl_xor(m, o));
        float e = (t < KN) ? __expf(sc - m) : 0.f;
        float ssum = e;
        for (int o = 32; o; o >>= 1) ssum += __shfl_xor(ssum, o);
        if (t < KN) wts[t] = e / ssum;
    }
    __syncthreads();

    float agg = 0.f;
#pragma unroll 10
    for (int k = 0; k < KN; ++k) agg += wts[k] * bf2f(projb[k * PS2 + t]);
    aggs[t] = agg;
    __syncthreads();

    if (t < 64) {
        const float4* w1 = reinterpret_cast<const float4*>(cg_W1 + t * 128);
        const float4* a4 = reinterpret_cast<const float4*>(aggs);
        float acc = cg_b1[t];
#pragma unroll 8
        for (int d = 0; d < 32; ++d) {
            float4 a = a4[d], ww = w1[d];
            acc += a.x * ww.x + a.y * ww.y + a.z * ww.z + a.w * ww.w;
        }
        float s = acc;
        for (int o = 32; o; o >>= 1) s += __shfl_xor(s, o);
        float mean = s * (1.f / 64.f);
        float dv = acc - mean;
        float vs = dv * dv;
        for (int o = 32; o; o >>= 1) vs += __shfl_xor(vs, o);
        float var = vs * (1.f / 64.f);
        float hv = dv * rsqrtf(var + 1e-5f) * cg_ln_g[t] + cg_ln_b[t];
        hv = fmaxf(hv, 0.f);
        float lg = hv * cg_W2[t];
        for (int o = 32; o; o >>= 1) lg += __shfl_xor(lg, o);
        if (t == 0) {
            lg += cg_b2[0];
            float temp = fminf(fmaxf(temp_p[0], 0.1f), 5.0f);
            float gate = sigm(lg / temp);
            gate_s = (deg[n] > 0) ? gate : 0.f;
        }
    }
    __syncthreads();

    float o = tanhf(self_e + gate_s * aggs[t]);
    size_t off = (size_t)orow * 256 + (size_t)side * 128 + t;
    outv[off] = o;
    outbf[off] = f2bf_rn(o);
}

// ---------------- LN (+residual) ----------------

__global__ void k_ln(const float* __restrict__ se2out, const float* __restrict__ x,
                     const float* __restrict__ g, const float* __restrict__ b,
                     float* __restrict__ enc, short* __restrict__ AHa, int M) {
    int wave = threadIdx.x >> 6, lane = threadIdx.x & 63;
    int row = blockIdx.x * 4 + wave;
    if (row >= M) return;
    const float* pr = se2out + (size_t)row * 256;
    const float* px = x + (size_t)row * 256;
    float v[4];
    float s = 0.f;
#pragma unroll
    for (int i = 0; i < 4; ++i) { v[i] = pr[lane + 64 * i] + px[lane + 64 * i]; s += v[i]; }
    for (int o = 32; o; o >>= 1) s += __shfl_xor(s, o);
    float mean = s * (1.f / 256.f);
    float vs = 0.f;
#pragma unroll
    for (int i = 0; i < 4; ++i) { float d = v[i] - mean; vs += d * d; }
    for (int o = 32; o; o >>= 1) vs += __shfl_xor(vs, o);
    float inv = rsqrtf(vs * (1.f / 256.f) + 1e-5f);
#pragma unroll
    for (int i = 0; i < 4; ++i) {
        int col = lane + 64 * i;
        float ov = (v[i] - mean) * inv * g[col] + b[col];
        enc[(size_t)row * 256 + col] = ov;
        if (row < 4096) AHa[(size_t)row * 512 + col] = f2bf_rn(ov);
    }
}

// ---------------- support mean + permuted LSTM biases ----------------

__global__ void k_whhbias(const float* __restrict__ enc, const float* __restrict__ Whh,
                          const float* __restrict__ bih, const float* __restrict__ bhh,
                          float* __restrict__ sg, float* __restrict__ bias_a,
                          float* __restrict__ whh_r) {
    __shared__ __align__(16) float sgs[256];
    int t = threadIdx.x;
    float s0 = 0.f;
#pragma unroll
    for (int i = 0; i < 5; ++i) s0 += enc[(size_t)(4096 + i) * 256 + t];
    s0 *= 0.2f;
    sgs[t] = s0;
    if (blockIdx.x == 0) sg[t] = s0;
    __syncthreads();

    int c = blockIdx.x * 256 + t;
    int nn = lstm_perm(c);
    const float4* wr = reinterpret_cast<const float4*>(Whh + (size_t)nn * 512 + 256);
    const float4* g4 = reinterpret_cast<const float4*>(sgs);
    float s = 0.f;
#pragma unroll 8
    for (int q = 0; q < 64; ++q) {
        float4 a = g4[q], ww = wr[q];
        s += a.x * ww.x + a.y * ww.y + a.z * ww.z + a.w * ww.w;
    }
    bias_a[c] = bih[nn] + bhh[nn];
    whh_r[c] = s;
}

__global__ void k_dot(const float* __restrict__ h, const float* __restrict__ gvec,
                      float* __restrict__ out) {
    int wave = threadIdx.x >> 6, lane = threadIdx.x & 63;
    int n = blockIdx.x * 4 + wave;
    if (n >= 4096) return;
    const float* p = h + (size_t)n * 256;
    float s = 0.f;
#pragma unroll
    for (int i = 0; i < 4; ++i) s += p[lane + 64 * i] * gvec[lane + 64 * i];
    for (int o = 32; o; o >>= 1) s += __shfl_xor(s, o);
    if (!lane) out[n] = s;
}

// ---------------- launch ----------------

extern "C" void kernel_launch(void* const* d_in, const int* in_sizes, int n_in,
                              void* d_out, int out_size, void* d_ws, size_t ws_size,
                              hipStream_t stream) {
    const int* query     = (const int*)d_in[0];
    const int* support   = (const int*)d_in[1];
    const int* q_l1      = (const int*)d_in[2];
    const int* q_deg_l   = (const int*)d_in[3];
    const int* q_r1      = (const int*)d_in[4];
    const int* q_deg_r   = (const int*)d_in[5];
    const int* s_l1      = (const int*)d_in[6];
    const int* s_deg_l   = (const int*)d_in[7];
    const int* s_r1      = (const int*)d_in[8];
    const int* s_deg_r   = (const int*)d_in[9];
    const float* emb     = (const float*)d_in[10];
    const float* gcn_W   = (const float*)d_in[11];
    const float* gcn_lin_b = (const float*)d_in[12];
    const float* gcn_b   = (const float*)d_in[13];
    const float* gate_temp = (const float*)d_in[14];
    const float* cg_W1   = (const float*)d_in[15];
    const float* cg_b1   = (const float*)d_in[16];
    const float* cg_ln_g = (const float*)d_in[17];
    const float* cg_ln_b = (const float*)d_in[18];
    const float* cg_W2   = (const float*)d_in[19];
    const float* cg_b2   = (const float*)d_in[20];
    const float* se_W1   = (const float*)d_in[21];
    const float* se_b1   = (const float*)d_in[22];
    const float* se_W2   = (const float*)d_in[23];
    const float* se_b2   = (const float*)d_in[24];
    const float* se_ln_g = (const float*)d_in[25];
    const float* se_ln_b = (const float*)d_in[26];
    const float* lstm_Wih = (const float*)d_in[27];
    const float* lstm_Whh = (const float*)d_in[28];
    const float* lstm_bih = (const float*)d_in[29];
    const float* lstm_bhh = (const float*)d_in[30];

    char* ws = (char*)d_ws;
    unsigned char* T = (unsigned char*)(ws + 0);    // 200001*256 fp8 = 51,200,256 (dead after neigh)
    short* h1bf    = (short*)(ws + 0);              // overlay
    float* se2out  = (float*)(ws + 4199424);
    float* enc     = (float*)(ws + 8398848);
    float* cbuf    = (float*)(ws + 12598272);       // 4096*512*4
    float* hbuf    = (float*)(ws + 20986880);       // 4096*256*4
    short* AHa     = (short*)(ws + 25181184);       // 4096*512*2
    short* AHb     = (short*)(ws + 29375488);       // 4096*512*2
    unsigned char* G0f = (unsigned char*)(ws + 33569792);  // 4096*512*4 fp8 = 8,388,608
    float* qsvec   = (float*)(ws + 102400512);
    short* qsbf    = (short*)(ws + 106599936);
    short* Bmat    = (short*)(ws + 108699648);
    float* bias256 = (float*)(ws + 108765184);
    short* sw1     = (short*)(ws + 108766208);
    short* sw2     = (short*)(ws + 109028352);
    short* Bih     = (short*)(ws + 109290496);
    short* Bhh     = (short*)(ws + 110339072);
    float* sg      = (float*)(ws + 111387648);
    float* bias_a  = (float*)(ws + 111388672);
    float* whh_r   = (float*)(ws + 111396864);
    float* outp    = (float*)d_out;

    k_prep<<<5248, 256, 0, stream>>>(se_W1, se_W2, gcn_W, gcn_lin_b, gcn_b,
                                     lstm_Wih, lstm_Whh, sw1, sw2, Bmat, bias256, Bih, Bhh);

    k_table<<<dim3(2, 384), 256, 0, stream>>>(emb, Bmat, bias256, T);

    k_neigh<<<8202, 128, 0, stream>>>(q_l1, q_deg_l, q_r1, q_deg_r,
        s_l1, s_deg_l, s_r1, s_deg_r, query, support, emb, T,
        cg_W1, cg_b1, cg_ln_g, cg_ln_b, cg_W2, cg_b2, gate_temp, qsvec, qsbf);

    gemm_bt<true, true><<<dim3(4, 33), 256, 0, stream>>>(
        qsbf, 256, sw1, 256, nullptr, h1bf, 512, se_b1, 4101, 512, 256);
    gemm_bt<false, false><<<dim3(2, 33), 256, 0, stream>>>(
        h1bf, 512, sw2, 512, se2out, nullptr, 256, se_b2, 4101, 256, 512);
    k_ln<<<1026, 256, 0, stream>>>(se2out, qsvec, se_ln_g, se_ln_b, enc, AHa, 4101);

    k_whhbias<<<8, 256, 0, stream>>>(enc, lstm_Whh, lstm_bih, lstm_bhh, sg, bias_a, whh_r);

    gemm_g0<<<dim3(16, 32), 256, 0, stream>>>(AHa, Bih, bias_a, cbuf, enc, AHb, G0f);

    gemm_lstm2<<<dim3(16, 32), 256, 0, stream>>>(
        AHb + 256, Bhh, G0f, whh_r, cbuf, enc, hbuf, AHa, 0);
    gemm_lstm2<<<dim3(16, 32), 256, 0, stream>>>(
        AHa + 256, Bhh, G0f, whh_r, cbuf, enc, hbuf, AHb, 0);
    gemm_lstm2<<<dim3(16, 32), 256, 0, stream>>>(
        AHb + 256, Bhh, G0f, whh_r, cbuf, enc, hbuf, AHa, 1);

    k_dot<<<1024, 256, 0, stream>>>(hbuf, sg, outp);
}

// Round 15
// 234.581 us; speedup vs baseline: 1.0577x; 1.0082x over previous
//
#include <hip/hip_runtime.h>
#include <hip/hip_bf16.h>
#include <cstdint>
#include <cstddef>

#define PAD_IDX 200000
#define KN 50
#define MROWS 200001

using frag8 = __attribute__((ext_vector_type(8))) short;
using f32x4 = __attribute__((ext_vector_type(4))) float;
using f32x2 = __attribute__((ext_vector_type(2))) float;

__device__ __forceinline__ short f2bf_rn(float v) {
    __hip_bfloat16 h = __float2bfloat16(v);
    union { __hip_bfloat16 h; short s; } u; u.h = h; return u.s;
}
__device__ __forceinline__ float bf2f(short s) {
    union { uint32_t u; float f; } x; x.u = ((uint32_t)(uint16_t)s) << 16;
    return x.f;
}
__device__ __forceinline__ float sigm(float x) { return 1.f / (1.f + __expf(-x)); }

// native OCP e4m3 converts (gfx950 fp8-conversion-insts)
__device__ __forceinline__ unsigned char f2fp8(float v) {
    int r = __builtin_amdgcn_cvt_pk_fp8_f32(v, v, 0, false);
    return (unsigned char)(r & 0xFF);
}
__device__ __forceinline__ void dec8(uint32_t lo, uint32_t hi, float* f) {
    f32x2 v0 = __builtin_amdgcn_cvt_pk_f32_fp8(lo, false);
    f32x2 v1 = __builtin_amdgcn_cvt_pk_f32_fp8(lo, true);
    f32x2 v2 = __builtin_amdgcn_cvt_pk_f32_fp8(hi, false);
    f32x2 v3 = __builtin_amdgcn_cvt_pk_f32_fp8(hi, true);
    f[0] = v0[0]; f[1] = v0[1]; f[2] = v1[0]; f[3] = v1[1];
    f[4] = v2[0]; f[5] = v2[1]; f[6] = v3[0]; f[7] = v3[1];
}

__device__ __forceinline__ int lstm_perm(int c) {
    int u = c >> 6, g = (c >> 4) & 3, v = c & 15;
    return (g << 9) + (u << 4) + v;
}

// ---------------- fused prep ----------------
__global__ void k_prep(const float* __restrict__ se_W1, const float* __restrict__ se_W2,
                       const float* __restrict__ gcn_W, const float* __restrict__ lin_b,
                       const float* __restrict__ gb,
                       const float* __restrict__ Wih, const float* __restrict__ Whh,
                       short* __restrict__ sw1, short* __restrict__ sw2,
                       short* __restrict__ Bmat, float* __restrict__ bias256,
                       short* __restrict__ Bih, short* __restrict__ Bhh) {
    int b = blockIdx.x, t = threadIdx.x;
    if (b < 512) {
        int i = b * 256 + t;
        sw1[i] = f2bf_rn(se_W1[i]);
    } else if (b < 1024) {
        int i = (b - 512) * 256 + t;
        sw2[i] = f2bf_rn(se_W2[i]);
    } else if (b < 1152) {
        int i = (b - 1024) * 256 + t;
        int n = i >> 7, k = i & 127;
        float v = (n < 128) ? gcn_W[n * 256 + k] : gcn_W[(n - 128) * 256 + 128 + k];
        Bmat[i] = f2bf_rn(v);
        if (k == 0) bias256[n] = (n < 128) ? 0.f : (lin_b[n - 128] + gb[n - 128]);
    } else {
        int i = (b - 1152) * 256 + t;   // 0 .. 2048*512
        int c = i >> 9, k = i & 511;
        int n = lstm_perm(c);
        if (k < 256) Bih[c * 256 + k] = f2bf_rn(Wih[n * 256 + k]);
        else         Bhh[c * 256 + (k - 256)] = f2bf_rn(Whh[(size_t)n * 512 + (k - 256)]);
    }
}

// ---------------- streaming table kernel v5: FP8 (e4m3, x16 scale) output ----------------

#define NT_TAB 3126   // ceil(200001/64)

#define TAB_ISSUE(PV, m0i) {                                                   \
    int row_ = (m0i) + rbase + l15;                                            \
    const float* p_ = emb + (size_t)row_ * 128 + (lk << 3);                    \
    if (row_ < MROWS) {                                                        \
        PV[0] = *reinterpret_cast<const float4*>(p_);                          \
        PV[1] = *reinterpret_cast<const float4*>(p_ + 4);                      \
        PV[2] = *reinterpret_cast<const float4*>(p_ + 32);                     \
        PV[3] = *reinterpret_cast<const float4*>(p_ + 36);                     \
        PV[4] = *reinterpret_cast<const float4*>(p_ + 64);                     \
        PV[5] = *reinterpret_cast<const float4*>(p_ + 68);                     \
        PV[6] = *reinterpret_cast<const float4*>(p_ + 96);                     \
        PV[7] = *reinterpret_cast<const float4*>(p_ + 100);                    \
    } else {                                                                   \
        PV[0] = z4; PV[1] = z4; PV[2] = z4; PV[3] = z4;                        \
        PV[4] = z4; PV[5] = z4; PV[6] = z4; PV[7] = z4;                        \
    } }

#define TAB_COMPUTE(PV, m0i) {                                                 \
    f32x4 acc[8] = {};                                                         \
    _Pragma("unroll")                                                          \
    for (int kf = 0; kf < 4; ++kf) {                                           \
        float4 vlo = PV[kf * 2], vhi = PV[kf * 2 + 1];                         \
        frag8 av;                                                              \
        av[0] = f2bf_rn(vlo.x); av[1] = f2bf_rn(vlo.y);                        \
        av[2] = f2bf_rn(vlo.z); av[3] = f2bf_rn(vlo.w);                        \
        av[4] = f2bf_rn(vhi.x); av[5] = f2bf_rn(vhi.y);                        \
        av[6] = f2bf_rn(vhi.z); av[7] = f2bf_rn(vhi.w);                        \
        _Pragma("unroll")                                                      \
        for (int fn = 0; fn < 8; ++fn) {                                       \
            frag8 bf = *reinterpret_cast<const frag8*>(                        \
                &Bs2[((fn * 4 + kf) * 64 + lane) * 8]);                        \
            acc[fn] = __builtin_amdgcn_mfma_f32_16x16x32_bf16(av, bf, acc[fn], 0, 0, 0); \
        }                                                                      \
    }                                                                          \
    _Pragma("unroll")                                                          \
    for (int fn = 0; fn < 8; ++fn)                                             \
        _Pragma("unroll")                                                      \
        for (int j = 0; j < 4; ++j)                                            \
            bounce8[(rbase + (lk << 2) + j) * 272 + fn * 16 + l15] =           \
                f2fp8((acc[fn][j] + bc[fn]) * 16.f);                           \
    _Pragma("unroll")                                                          \
    for (int p = 0; p < 2; ++p) {                                              \
        int idx = p * 64 + lane;                                               \
        int rl = idx >> 3, ch = idx & 7;                                       \
        int grow = (m0i) + rbase + rl;                                         \
        if (grow < MROWS) {                                                    \
            int4 v = *reinterpret_cast<const int4*>(&bounce8[(rbase + rl) * 272 + ch * 16]); \
            *reinterpret_cast<int4*>(T + (size_t)grow * 256 + n0 + ch * 16) = v; \
        }                                                                      \
    } }

__global__ __launch_bounds__(256, 3) void k_table(
    const float* __restrict__ emb, const short* __restrict__ Bmat,
    const float* __restrict__ bias256, unsigned char* __restrict__ T)
{
    __shared__ short Bs2[32 * 64 * 8];                        // 32 KB frag-linear B
    __shared__ __align__(16) unsigned char bounce8[64 * 272]; // 17 KB fp8 bounce
    const int t = threadIdx.x, lane = t & 63, w = t >> 6;
    const int n0 = blockIdx.x * 128;
    const int l15 = lane & 15, lk = lane >> 4;
    const int rbase = w * 16;
    const float4 z4 = {0.f, 0.f, 0.f, 0.f};

#pragma unroll
    for (int i = 0; i < 8; ++i) {
        int slot = i * 256 + t;          // 0..2047
        int fk = slot >> 6, ln = slot & 63;
        int fn = fk >> 2, kf = fk & 3;
        frag8 bv = *reinterpret_cast<const frag8*>(
            Bmat + (n0 + fn * 16 + (ln & 15)) * 128 + kf * 32 + ((ln >> 4) << 3));
        *reinterpret_cast<frag8*>(&Bs2[slot * 8]) = bv;
    }
    float bc[8];
#pragma unroll
    for (int fn = 0; fn < 8; ++fn) bc[fn] = bias256[n0 + fn * 16 + l15];
    __syncthreads();

    float4 pvA[8], pvB[8];
    int tile = blockIdx.y;
    const int stride = gridDim.y;
    if (tile < NT_TAB) TAB_ISSUE(pvA, tile * 64);
    for (; tile < NT_TAB; tile += 2 * stride) {
        int t1 = tile + stride;
        if (t1 < NT_TAB) TAB_ISSUE(pvB, t1 * 64);
        TAB_COMPUTE(pvA, tile * 64);
        int t2 = tile + 2 * stride;
        if (t2 < NT_TAB) TAB_ISSUE(pvA, t2 * 64);
        if (t1 < NT_TAB) TAB_COMPUTE(pvB, t1 * 64);
    }
}

// ---------------- generic MFMA GEMM: C = A@B^T (+bias) ----------------

constexpr int SA = 40;
constexpr int CS = 132;

template<bool RELU, bool OUTBF>
__global__ __launch_bounds__(256) void gemm_bt(
    const short* __restrict__ A, int lda, const short* __restrict__ B, int ldb,
    float* __restrict__ C, short* __restrict__ Cbf, int ldc,
    const float* __restrict__ bias, int M, int N, int K)
{
    __shared__ short sh[2 * 128 * SA];
    short* As = sh;
    short* Bs = sh + 128 * SA;
    const int t = threadIdx.x;
    const int m0 = blockIdx.y * 128, n0 = blockIdx.x * 128;
    const int wave = t >> 6, lane = t & 63;
    const int wr = wave >> 1, wc = wave & 1;
    f32x4 acc[4][4] = {};
    for (int k0 = 0; k0 < K; k0 += 32) {
#pragma unroll
        for (int i = 0; i < 2; ++i) {
            int idx = t + i * 256;
            int r = idx >> 2, c8 = (idx & 3) << 3;
            frag8 av = {0, 0, 0, 0, 0, 0, 0, 0};
            int arow = m0 + r;
            if (arow < M)
                av = *reinterpret_cast<const frag8*>(A + (size_t)arow * lda + k0 + c8);
            *reinterpret_cast<frag8*>(&As[r * SA + c8]) = av;
            frag8 bv = *reinterpret_cast<const frag8*>(B + (size_t)(n0 + r) * ldb + k0 + c8);
            *reinterpret_cast<frag8*>(&Bs[r * SA + c8]) = bv;
        }
        __syncthreads();
        frag8 af[4], bfv[4];
#pragma unroll
        for (int f = 0; f < 4; ++f) {
            af[f]  = *reinterpret_cast<const frag8*>(&As[(wr * 64 + f * 16 + (lane & 15)) * SA + ((lane >> 4) << 3)]);
            bfv[f] = *reinterpret_cast<const frag8*>(&Bs[(wc * 64 + f * 16 + (lane & 15)) * SA + ((lane >> 4) << 3)]);
        }
#pragma unroll
        for (int fm = 0; fm < 4; ++fm)
#pragma unroll
            for (int fn = 0; fn < 4; ++fn)
                acc[fm][fn] = __builtin_amdgcn_mfma_f32_16x16x32_bf16(af[fm], bfv[fn], acc[fm][fn], 0, 0, 0);
        __syncthreads();
    }

    if constexpr (OUTBF) {
#pragma unroll
        for (int half = 0; half < 2; ++half) {
            if (wr == half) {
#pragma unroll
                for (int fm = 0; fm < 4; ++fm) {
                    int rl = fm * 16 + ((lane >> 4) << 2);
#pragma unroll
                    for (int fn = 0; fn < 4; ++fn) {
                        int col = wc * 64 + fn * 16 + (lane & 15);
                        float bcv = bias[n0 + col];
#pragma unroll
                        for (int j = 0; j < 4; ++j) {
                            float v = acc[fm][fn][j] + bcv;
                            if (RELU) v = fmaxf(v, 0.f);
                            sh[(rl + j) * CS + col] = f2bf_rn(v);
                        }
                    }
                }
            }
            __syncthreads();
#pragma unroll
            for (int p = 0; p < 4; ++p) {
                int off16 = p * 256 + t;
                int rl = off16 >> 4, ch = off16 & 15;
                int rr = m0 + half * 64 + rl;
                if (rr < M) {
                    frag8 val = *reinterpret_cast<const frag8*>(&sh[rl * CS + ch * 8]);
                    *reinterpret_cast<frag8*>(&Cbf[(size_t)rr * ldc + n0 + ch * 8]) = val;
                }
            }
            __syncthreads();
        }
    } else {
#pragma unroll
        for (int fm = 0; fm < 4; ++fm) {
            int rowb = m0 + wr * 64 + fm * 16 + ((lane >> 4) << 2);
#pragma unroll
            for (int fn = 0; fn < 4; ++fn) {
                int col = n0 + wc * 64 + fn * 16 + (lane & 15);
                float bcv = bias[col];
#pragma unroll
                for (int j = 0; j < 4; ++j) {
                    int rr = rowb + j;
                    if (rr < M) {
                        float v = acc[fm][fn][j] + bcv;
                        if (RELU) v = fmaxf(v, 0.f);
                        C[(size_t)rr * ldc + col] = v;
                    }
                }
            }
        }
    }
}

// ---------------- G0 GEMM + fused LSTM step 0 (G0 fp8 x8; c stored bf16) ----------------

__global__ __launch_bounds__(256) void gemm_g0(
    const short* __restrict__ A, const short* __restrict__ Bih,
    const float* __restrict__ bias_a, short* __restrict__ cbufh,
    const float* __restrict__ enc, short* __restrict__ AHnext,
    unsigned char* __restrict__ G0f)
{
    __shared__ short sh[2 * 128 * SA];
    short* As = sh;
    short* Bs = sh + 128 * SA;
    const int t = threadIdx.x;
    const int m0 = blockIdx.y * 128, n0 = blockIdx.x * 128;
    const int wave = t >> 6, lane = t & 63;
    const int wr = wave >> 1, wc = wave & 1;
    f32x4 acc[4][4] = {};
    for (int k0 = 0; k0 < 256; k0 += 32) {
#pragma unroll
        for (int i = 0; i < 2; ++i) {
            int idx = t + i * 256;
            int r = idx >> 2, c8 = (idx & 3) << 3;
            frag8 av = *reinterpret_cast<const frag8*>(A + (size_t)(m0 + r) * 512 + k0 + c8);
            *reinterpret_cast<frag8*>(&As[r * SA + c8]) = av;
            frag8 bv = *reinterpret_cast<const frag8*>(Bih + (size_t)(n0 + r) * 256 + k0 + c8);
            *reinterpret_cast<frag8*>(&Bs[r * SA + c8]) = bv;
        }
        __syncthreads();
        frag8 af[4], bfv[4];
#pragma unroll
        for (int f = 0; f < 4; ++f) {
            af[f]  = *reinterpret_cast<const frag8*>(&As[(wr * 64 + f * 16 + (lane & 15)) * SA + ((lane >> 4) << 3)]);
            bfv[f] = *reinterpret_cast<const frag8*>(&Bs[(wc * 64 + f * 16 + (lane & 15)) * SA + ((lane >> 4) << 3)]);
        }
#pragma unroll
        for (int fm = 0; fm < 4; ++fm)
#pragma unroll
            for (int fn = 0; fn < 4; ++fn)
                acc[fm][fn] = __builtin_amdgcn_mfma_f32_16x16x32_bf16(af[fm], bfv[fn], acc[fm][fn], 0, 0, 0);
        __syncthreads();
    }

    const int v = lane & 15;
    const int colbase = n0 + wc * 64;
    const int j = ((blockIdx.x * 2 + wc) << 4) + v;   // unit 0..511
    float bv0 = bias_a[colbase + v];
    float bv1 = bias_a[colbase + 16 + v];
    float bv2 = bias_a[colbase + 32 + v];
    float bv3 = bias_a[colbase + 48 + v];
#pragma unroll
    for (int fm = 0; fm < 4; ++fm) {
        int rowb = m0 + wr * 64 + fm * 16 + ((lane >> 4) << 2);
#pragma unroll
        for (int jr = 0; jr < 4; ++jr) {
            int row = rowb + jr;
            float gi = acc[fm][0][jr] + bv0;
            float gf = acc[fm][1][jr] + bv1;
            float gg = acc[fm][2][jr] + bv2;
            float go = acc[fm][3][jr] + bv3;
            int r8 = __builtin_amdgcn_cvt_pk_fp8_f32(gi * 8.f, gf * 8.f, 0, false);
            r8 = __builtin_amdgcn_cvt_pk_fp8_f32(gg * 8.f, go * 8.f, r8, true);
            *reinterpret_cast<unsigned int*>(G0f + ((size_t)row * 512 + j) * 4) = (unsigned int)r8;
            float cn = sigm(gi) * tanhf(gg);          // c_prev = 0
            cbufh[(size_t)row * 512 + j] = f2bf_rn(cn);
            float hc = sigm(go) * tanhf(cn);
            if (j < 256) {
                float hv = enc[(size_t)row * 256 + j] + hc;
                AHnext[(size_t)row * 512 + 256 + j] = f2bf_rn(hv);
            }
        }
    }
}

// ---------------- LSTM steps 1-3 (c bf16) ----------------

__global__ __launch_bounds__(256) void gemm_lstm2(
    const short* __restrict__ A, const short* __restrict__ Bp,
    const unsigned char* __restrict__ G0f, const float* __restrict__ whh_r,
    short* __restrict__ cbufh, const float* __restrict__ enc,
    float* __restrict__ hbuf, short* __restrict__ AHnext, int last)
{
    __shared__ short sh[2 * 128 * SA];
    short* As = sh;
    short* Bs = sh + 128 * SA;
    const int t = threadIdx.x;
    const int m0 = blockIdx.y * 128, n0 = blockIdx.x * 128;
    const int wave = t >> 6, lane = t & 63;
    const int wr = wave >> 1, wc = wave & 1;
    f32x4 acc[4][4] = {};
    for (int k0 = 0; k0 < 256; k0 += 32) {
#pragma unroll
        for (int i = 0; i < 2; ++i) {
            int idx = t + i * 256;
            int r = idx >> 2, c8 = (idx & 3) << 3;
            frag8 av = *reinterpret_cast<const frag8*>(A + (size_t)(m0 + r) * 512 + k0 + c8);
            *reinterpret_cast<frag8*>(&As[r * SA + c8]) = av;
            frag8 bv = *reinterpret_cast<const frag8*>(Bp + (size_t)(n0 + r) * 256 + k0 + c8);
            *reinterpret_cast<frag8*>(&Bs[r * SA + c8]) = bv;
        }
        __syncthreads();
        frag8 af[4], bfv[4];
#pragma unroll
        for (int f = 0; f < 4; ++f) {
            af[f]  = *reinterpret_cast<const frag8*>(&As[(wr * 64 + f * 16 + (lane & 15)) * SA + ((lane >> 4) << 3)]);
            bfv[f] = *reinterpret_cast<const frag8*>(&Bs[(wc * 64 + f * 16 + (lane & 15)) * SA + ((lane >> 4) << 3)]);
        }
#pragma unroll
        for (int fm = 0; fm < 4; ++fm)
#pragma unroll
            for (int fn = 0; fn < 4; ++fn)
                acc[fm][fn] = __builtin_amdgcn_mfma_f32_16x16x32_bf16(af[fm], bfv[fn], acc[fm][fn], 0, 0, 0);
        __syncthreads();
    }

    const int v = lane & 15;
    const int colbase = n0 + wc * 64;
    const int j = ((blockIdx.x * 2 + wc) << 4) + v;
    float wr0 = whh_r[colbase + v];
    float wr1 = whh_r[colbase + 16 + v];
    float wr2 = whh_r[colbase + 32 + v];
    float wr3 = whh_r[colbase + 48 + v];
#pragma unroll
    for (int fm = 0; fm < 4; ++fm) {
        int rowb = m0 + wr * 64 + fm * 16 + ((lane >> 4) << 2);
#pragma unroll
        for (int jr = 0; jr < 4; ++jr) {
            int row = rowb + jr;
            unsigned int u = *reinterpret_cast<const unsigned int*>(G0f + ((size_t)row * 512 + j) * 4);
            f32x2 g01 = __builtin_amdgcn_cvt_pk_f32_fp8(u, false);
            f32x2 g23 = __builtin_amdgcn_cvt_pk_f32_fp8(u, true);
            float gi = acc[fm][0][jr] + g01[0] * 0.125f + wr0;
            float gf = acc[fm][1][jr] + g01[1] * 0.125f + wr1;
            float gg = acc[fm][2][jr] + g23[0] * 0.125f + wr2;
            float go = acc[fm][3][jr] + g23[1] * 0.125f + wr3;
            size_t cidx = (size_t)row * 512 + j;
            float cn = sigm(gf) * bf2f(cbufh[cidx]) + sigm(gi) * tanhf(gg);
            cbufh[cidx] = f2bf_rn(cn);
            float hc = sigm(go) * tanhf(cn);
            if (j < 256) {
                float hv = enc[(size_t)row * 256 + j] + hc;
                AHnext[(size_t)row * 512 + 256 + j] = f2bf_rn(hv);
                if (last) hbuf[(size_t)row * 256 + j] = hv;
            }
        }
    }
}

// ---------------- fused neigh v10: 16B/lane fp8 gathers (8 loads), fused score ----------------

constexpr int PS2 = 136;

__global__ __launch_bounds__(128) void k_neigh(
    const int* __restrict__ q_l1, const int* __restrict__ q_deg_l,
    const int* __restrict__ q_r1, const int* __restrict__ q_deg_r,
    const int* __restrict__ s_l1, const int* __restrict__ s_deg_l,
    const int* __restrict__ s_r1, const int* __restrict__ s_deg_r,
    const int* __restrict__ query, const int* __restrict__ support,
    const float* __restrict__ emb, const unsigned char* __restrict__ T,
    const float* __restrict__ cg_W1, const float* __restrict__ cg_b1,
    const float* __restrict__ cg_ln_g, const float* __restrict__ cg_ln_b,
    const float* __restrict__ cg_W2, const float* __restrict__ cg_b2,
    const float* __restrict__ temp_p,
    float* __restrict__ outv, short* __restrict__ outbf)
{
    int b = blockIdx.x;
    const int* conns; const int* deg; const int* ids2; int side, n, orow;
    if (b < 4096)      { conns = q_l1; deg = q_deg_l; ids2 = query;   side = 0; n = b;        orow = n; }
    else if (b < 8192) { conns = q_r1; deg = q_deg_r; ids2 = query;   side = 1; n = b - 4096; orow = n; }
    else if (b < 8197) { conns = s_l1; deg = s_deg_l; ids2 = support; side = 0; n = b - 8192; orow = 4096 + n; }
    else               { conns = s_r1; deg = s_deg_r; ids2 = support; side = 1; n = b - 8197; orow = 4096 + n; }

    int t = threadIdx.x;  // 128
    __shared__ __align__(16) short projb[KN * PS2];
    __shared__ __align__(16) float se[128];
    __shared__ int rels[KN], ents[KN];
    __shared__ float wts[KN];
    __shared__ float scs[KN];
    __shared__ __align__(16) float aggs[128];
    __shared__ float gate_s;

    int self_id = ids2[n * 2 + side];
    float self_e = emb[(size_t)self_id * 128 + t];
    se[t] = self_e;
    if (t < KN) {
        rels[t] = conns[((size_t)n * KN + t) * 2];
        ents[t] = conns[((size_t)n * KN + t) * 2 + 1];
    }
    __syncthreads();

    // gather + score: k = it*16 + (t>>3), d0 = (t&7)*16. 16B/lane loads (8 total),
    // branch-free (clamped index, masked via pmask); score fused, 3-shfl reduce.
    {
        const int kq = t >> 3;            // 0..15
        const int d0 = (t & 7) << 4;      // 0..112
        uint4 ra0, ra1, ra2, ra3;
        uint4 rb0, rb1, rb2, rb3;
        int pmask = 0;

#define NB_LOAD(IT, RA, RB) {                                                  \
        int k_ = IT * 16 + kq;                                                 \
        int kc = k_ < KN ? k_ : KN - 1;                                        \
        int rv = rels[kc], ev = ents[kc];                                      \
        if (k_ >= KN || rv == PAD_IDX) pmask |= (1 << IT);                     \
        RA = *reinterpret_cast<const uint4*>(T + (size_t)rv * 256 + d0);       \
        RB = *reinterpret_cast<const uint4*>(T + (size_t)ev * 256 + 128 + d0); }
        NB_LOAD(0, ra0, rb0)
        NB_LOAD(1, ra1, rb1)
        NB_LOAD(2, ra2, rb2)
        NB_LOAD(3, ra3, rb3)
#undef NB_LOAD

        float se0[16];
        *reinterpret_cast<float4*>(&se0[0])  = *reinterpret_cast<const float4*>(&se[d0]);
        *reinterpret_cast<float4*>(&se0[4])  = *reinterpret_cast<const float4*>(&se[d0 + 4]);
        *reinterpret_cast<float4*>(&se0[8])  = *reinterpret_cast<const float4*>(&se[d0 + 8]);
        *reinterpret_cast<float4*>(&se0[12]) = *reinterpret_cast<const float4*>(&se[d0 + 12]);

#define NB_PROC(IT, RA, RB) {                                                  \
        int k_ = IT * 16 + kq;                                                 \
        float fa[16], fb[16];                                                  \
        dec8(RA.x, RA.y, fa); dec8(RA.z, RA.w, fa + 8);                        \
        dec8(RB.x, RB.y, fb); dec8(RB.z, RB.w, fb + 8);                        \
        frag8 pv0, pv1; float prt = 0.f;                                       \
        _Pragma("unroll")                                                      \
        for (int q = 0; q < 8; ++q) {                                          \
            float raw = (fa[q] + fb[q]) * 0.0625f;                             \
            float pl = raw > 0.f ? raw : 0.01f * raw;                          \
            pv0[q] = f2bf_rn(pl);                                              \
            prt += pl * se0[q];                                                \
        }                                                                      \
        _Pragma("unroll")                                                      \
        for (int q = 0; q < 8; ++q) {                                          \
            float raw = (fa[8 + q] + fb[8 + q]) * 0.0625f;                     \
            float pl = raw > 0.f ? raw : 0.01f * raw;                          \
            pv1[q] = f2bf_rn(pl);                                              \
            prt += pl * se0[8 + q];                                            \
        }                                                                      \
        prt += __shfl_xor(prt, 1); prt += __shfl_xor(prt, 2);                  \
        prt += __shfl_xor(prt, 4);                                             \
        if (k_ < KN) {                                                         \
            *reinterpret_cast<frag8*>(&projb[k_ * PS2 + d0]) = pv0;            \
            *reinterpret_cast<frag8*>(&projb[k_ * PS2 + d0 + 8]) = pv1;        \
            if ((t & 7) == 0)                                                  \
                scs[k_] = ((pmask >> IT) & 1) ? -1e9f : prt;                   \
        } }
        NB_PROC(0, ra0, rb0)
        NB_PROC(1, ra1, rb1)
        NB_PROC(2, ra2, rb2)
        NB_PROC(3, ra3, rb3)
#undef NB_PROC
    }
    __syncthreads();

    if (t < 64) {
        float sc = (t < KN) ? scs[t] : -1e9f;
        float m = sc;
        for (int o = 32; o; o >>= 1) m = fmaxf(m, __shfl_xor(m, o));
        float e = (t < KN) ? __expf(sc - m) : 0.f;
        float ssum = e;
        for (int o = 32; o; o >>= 1) ssum += __shfl_xor(ssum, o);
        if (t < KN) wts[t] = e / ssum;
    }
    __syncthreads();

    float agg = 0.f;
#pragma unroll 10
    for (int k = 0; k < KN; ++k) agg += wts[k] * bf2f(projb[k * PS2 + t]);
    aggs[t] = agg;
    __syncthreads();

    if (t < 64) {
        const float4* w1 = reinterpret_cast<const float4*>(cg_W1 + t * 128);
        const float4* a4 = reinterpret_cast<const float4*>(aggs);
        float acc = cg_b1[t];
#pragma unroll 8
        for (int d = 0; d < 32; ++d) {
            float4 a = a4[d], ww = w1[d];
            acc += a.x * ww.x + a.y * ww.y + a.z * ww.z + a.w * ww.w;
        }
        float s = acc;
        for (int o = 32; o; o >>= 1) s += __shfl_xor(s, o);
        float mean = s * (1.f / 64.f);
        float dv = acc - mean;
        float vs = dv * dv;
        for (int o = 32; o; o >>= 1) vs += __shfl_xor(vs, o);
        float var = vs * (1.f / 64.f);
        float hv = dv * rsqrtf(var + 1e-5f) * cg_ln_g[t] + cg_ln_b[t];
        hv = fmaxf(hv, 0.f);
        float lg = hv * cg_W2[t];
        for (int o = 32; o; o >>= 1) lg += __shfl_xor(lg, o);
        if (t == 0) {
            lg += cg_b2[0];
            float temp = fminf(fmaxf(temp_p[0], 0.1f), 5.0f);
            float gate = sigm(lg / temp);
            gate_s = (deg[n] > 0) ? gate : 0.f;
        }
    }
    __syncthreads();

    float o = tanhf(self_e + gate_s * aggs[t]);
    size_t off = (size_t)orow * 256 + (size_t)side * 128 + t;
    outv[off] = o;
    outbf[off] = f2bf_rn(o);
}

// ---------------- LN (+residual) ----------------

__global__ void k_ln(const float* __restrict__ se2out, const float* __restrict__ x,
                     const float* __restrict__ g, const float* __restrict__ b,
                     float* __restrict__ enc, short* __restrict__ AHa, int M) {
    int wave = threadIdx.x >> 6, lane = threadIdx.x & 63;
    int row = blockIdx.x * 4 + wave;
    if (row >= M) return;
    const float* pr = se2out + (size_t)row * 256;
    const float* px = x + (size_t)row * 256;
    float v[4];
    float s = 0.f;
#pragma unroll
    for (int i = 0; i < 4; ++i) { v[i] = pr[lane + 64 * i] + px[lane + 64 * i]; s += v[i]; }
    for (int o = 32; o; o >>= 1) s += __shfl_xor(s, o);
    float mean = s * (1.f / 256.f);
    float vs = 0.f;
#pragma unroll
    for (int i = 0; i < 4; ++i) { float d = v[i] - mean; vs += d * d; }
    for (int o = 32; o; o >>= 1) vs += __shfl_xor(vs, o);
    float inv = rsqrtf(vs * (1.f / 256.f) + 1e-5f);
#pragma unroll
    for (int i = 0; i < 4; ++i) {
        int col = lane + 64 * i;
        float ov = (v[i] - mean) * inv * g[col] + b[col];
        enc[(size_t)row * 256 + col] = ov;
        if (row < 4096) AHa[(size_t)row * 512 + col] = f2bf_rn(ov);
    }
}

// ---------------- support mean + permuted LSTM biases ----------------

__global__ void k_whhbias(const float* __restrict__ enc, const float* __restrict__ Whh,
                          const float* __restrict__ bih, const float* __restrict__ bhh,
                          float* __restrict__ sg, float* __restrict__ bias_a,
                          float* __restrict__ whh_r) {
    __shared__ __align__(16) float sgs[256];
    int t = threadIdx.x;
    float s0 = 0.f;
#pragma unroll
    for (int i = 0; i < 5; ++i) s0 += enc[(size_t)(4096 + i) * 256 + t];
    s0 *= 0.2f;
    sgs[t] = s0;
    if (blockIdx.x == 0) sg[t] = s0;
    __syncthreads();

    int c = blockIdx.x * 256 + t;
    int nn = lstm_perm(c);
    const float4* wr = reinterpret_cast<const float4*>(Whh + (size_t)nn * 512 + 256);
    const float4* g4 = reinterpret_cast<const float4*>(sgs);
    float s = 0.f;
#pragma unroll 8
    for (int q = 0; q < 64; ++q) {
        float4 a = g4[q], ww = wr[q];
        s += a.x * ww.x + a.y * ww.y + a.z * ww.z + a.w * ww.w;
    }
    bias_a[c] = bih[nn] + bhh[nn];
    whh_r[c] = s;
}

__global__ void k_dot(const float* __restrict__ h, const float* __restrict__ gvec,
                      float* __restrict__ out) {
    int wave = threadIdx.x >> 6, lane = threadIdx.x & 63;
    int n = blockIdx.x * 4 + wave;
    if (n >= 4096) return;
    const float* p = h + (size_t)n * 256;
    float s = 0.f;
#pragma unroll
    for (int i = 0; i < 4; ++i) s += p[lane + 64 * i] * gvec[lane + 64 * i];
    for (int o = 32; o; o >>= 1) s += __shfl_xor(s, o);
    if (!lane) out[n] = s;
}

// ---------------- launch ----------------

extern "C" void kernel_launch(void* const* d_in, const int* in_sizes, int n_in,
                              void* d_out, int out_size, void* d_ws, size_t ws_size,
                              hipStream_t stream) {
    const int* query     = (const int*)d_in[0];
    const int* support   = (const int*)d_in[1];
    const int* q_l1      = (const int*)d_in[2];
    const int* q_deg_l   = (const int*)d_in[3];
    const int* q_r1      = (const int*)d_in[4];
    const int* q_deg_r   = (const int*)d_in[5];
    const int* s_l1      = (const int*)d_in[6];
    const int* s_deg_l   = (const int*)d_in[7];
    const int* s_r1      = (const int*)d_in[8];
    const int* s_deg_r   = (const int*)d_in[9];
    const float* emb     = (const float*)d_in[10];
    const float* gcn_W   = (const float*)d_in[11];
    const float* gcn_lin_b = (const float*)d_in[12];
    const float* gcn_b   = (const float*)d_in[13];
    const float* gate_temp = (const float*)d_in[14];
    const float* cg_W1   = (const float*)d_in[15];
    const float* cg_b1   = (const float*)d_in[16];
    const float* cg_ln_g = (const float*)d_in[17];
    const float* cg_ln_b = (const float*)d_in[18];
    const float* cg_W2   = (const float*)d_in[19];
    const float* cg_b2   = (const float*)d_in[20];
    const float* se_W1   = (const float*)d_in[21];
    const float* se_b1   = (const float*)d_in[22];
    const float* se_W2   = (const float*)d_in[23];
    const float* se_b2   = (const float*)d_in[24];
    const float* se_ln_g = (const float*)d_in[25];
    const float* se_ln_b = (const float*)d_in[26];
    const float* lstm_Wih = (const float*)d_in[27];
    const float* lstm_Whh = (const float*)d_in[28];
    const float* lstm_bih = (const float*)d_in[29];
    const float* lstm_bhh = (const float*)d_in[30];

    char* ws = (char*)d_ws;
    unsigned char* T = (unsigned char*)(ws + 0);    // 200001*256 fp8 = 51,200,256 (dead after neigh)
    short* h1bf    = (short*)(ws + 0);              // overlay
    float* se2out  = (float*)(ws + 4199424);
    float* enc     = (float*)(ws + 8398848);
    short* cbufh   = (short*)(ws + 12598272);       // 4096*512*2 bf16
    float* hbuf    = (float*)(ws + 20986880);       // 4096*256*4
    short* AHa     = (short*)(ws + 25181184);       // 4096*512*2
    short* AHb     = (short*)(ws + 29375488);       // 4096*512*2
    unsigned char* G0f = (unsigned char*)(ws + 33569792);  // 4096*512*4 fp8
    float* qsvec   = (float*)(ws + 102400512);
    short* qsbf    = (short*)(ws + 106599936);
    short* Bmat    = (short*)(ws + 108699648);
    float* bias256 = (float*)(ws + 108765184);
    short* sw1     = (short*)(ws + 108766208);
    short* sw2     = (short*)(ws + 109028352);
    short* Bih     = (short*)(ws + 109290496);
    short* Bhh     = (short*)(ws + 110339072);
    float* sg      = (float*)(ws + 111387648);
    float* bias_a  = (float*)(ws + 111388672);
    float* whh_r   = (float*)(ws + 111396864);
    float* outp    = (float*)d_out;

    k_prep<<<5248, 256, 0, stream>>>(se_W1, se_W2, gcn_W, gcn_lin_b, gcn_b,
                                     lstm_Wih, lstm_Whh, sw1, sw2, Bmat, bias256, Bih, Bhh);

    k_table<<<dim3(2, 384), 256, 0, stream>>>(emb, Bmat, bias256, T);

    k_neigh<<<8202, 128, 0, stream>>>(q_l1, q_deg_l, q_r1, q_deg_r,
        s_l1, s_deg_l, s_r1, s_deg_r, query, support, emb, T,
        cg_W1, cg_b1, cg_ln_g, cg_ln_b, cg_W2, cg_b2, gate_temp, qsvec, qsbf);

    gemm_bt<true, true><<<dim3(4, 33), 256, 0, stream>>>(
        qsbf, 256, sw1, 256, nullptr, h1bf, 512, se_b1, 4101, 512, 256);
    gemm_bt<false, false><<<dim3(2, 33), 256, 0, stream>>>(
        h1bf, 512, sw2, 512, se2out, nullptr, 256, se_b2, 4101, 256, 512);
    k_ln<<<1026, 256, 0, stream>>>(se2out, qsvec, se_ln_g, se_ln_b, enc, AHa, 4101);

    k_whhbias<<<8, 256, 0, stream>>>(enc, lstm_Whh, lstm_bih, lstm_bhh, sg, bias_a, whh_r);

    gemm_g0<<<dim3(16, 32), 256, 0, stream>>>(AHa, Bih, bias_a, cbufh, enc, AHb, G0f);

    gemm_lstm2<<<dim3(16, 32), 256, 0, stream>>>(
        AHb + 256, Bhh, G0f, whh_r, cbufh, enc, hbuf, AHa, 0);
    gemm_lstm2<<<dim3(16, 32), 256, 0, stream>>>(
        AHa + 256, Bhh, G0f, whh_r, cbufh, enc, hbuf, AHb, 0);
    gemm_lstm2<<<dim3(16, 32), 256, 0, stream>>>(
        AHb + 256, Bhh, G0f, whh_r, cbufh, enc, hbuf, AHa, 1);

    k_dot<<<1024, 256, 0, stream>>>(hbuf, sg, outp);
}